// Round 5
// baseline (109.647 us; speedup 1.0000x reference)
//
#include <hip/hip_runtime.h>

typedef unsigned int u32;
typedef unsigned long long u64;

#define BATCH 32
#define NPRI  200000
#define TOPK  200
#define CAP   4096             // max candidates per image
#define PRE_BITS 0x3F7C0000u   // bits of 0.984375f; hot-path capture threshold
#define LBUF  512              // per-block LDS candidate buffer (k_cap)
#define S16   16               // counter padding (64B lines)

// ws layout (u32 words)
#define W_NCAND  0
#define W_CNT001 (BATCH*S16)
#define W_FLAGS  (W_CNT001 + BATCH*S16)
#define ZWORDS   (W_FLAGS + BATCH)          // 1056 words; *4 = 4224 B (8B-aligned)
#define OUTN     (BATCH*2*TOPK*5)

// ---------------- zero ws counters + output ----------------
__global__ void k_zero(u32* __restrict__ wsw, float* __restrict__ out) {
  int stride = gridDim.x * blockDim.x;
  for (int i = blockIdx.x*blockDim.x + threadIdx.x; i < ZWORDS + OUTN; i += stride) {
    if (i < ZWORDS) wsw[i] = 0u;
    else out[i - ZWORDS] = 0.0f;
  }
}

// ------- hot path: single BW pass, capture scores >= 0.984375, count positives -------
__global__ __launch_bounds__(256) void k_cap(const float* __restrict__ conf,
                                             u32* __restrict__ ncand,
                                             u32* __restrict__ cnt001,
                                             u64* __restrict__ cand,
                                             u32* __restrict__ flags) {
  __shared__ u64 lbuf[LBUF];          // 4 KB
  __shared__ u32 lcnt, lbase, lc001;
  if (threadIdx.x == 0) { lcnt = 0u; lc001 = 0u; }
  __syncthreads();
  const int img = blockIdx.y;
  const float4* cp = ((const float4*)conf) + (size_t)img * (NPRI/2);
  u32 my001 = 0;
  for (int i = blockIdx.x*256 + threadIdx.x; i < NPRI/2; i += gridDim.x*256) {
    float4 v = cp[i];
    if (v.y > 0.01f) {
      ++my001;
      u32 bits = __float_as_uint(v.y);
      if (bits >= PRE_BITS) {
        u32 p = atomicAdd(&lcnt, 1u);
        if (p < LBUF) lbuf[p] = ((u64)bits << 32) | (u64)(0xFFFFFFFFu - (u32)(2*i));
      }
    }
    if (v.w > 0.01f) {
      ++my001;
      u32 bits = __float_as_uint(v.w);
      if (bits >= PRE_BITS) {
        u32 p = atomicAdd(&lcnt, 1u);
        if (p < LBUF) lbuf[p] = ((u64)bits << 32) | (u64)(0xFFFFFFFFu - (u32)(2*i+1));
      }
    }
  }
  atomicAdd(&lc001, my001);
  __syncthreads();
  if (threadIdx.x == 0) {
    atomicAdd(&cnt001[img * S16], lc001);
    u32 n = lcnt;
    if (n > LBUF) { n = LBUF; atomicOr(&flags[img], 1u); }
    lbase = atomicAdd(&ncand[img * S16], n);
    lcnt = n;
  }
  __syncthreads();
  u64* cd = cand + (size_t)img * CAP;
  u32 n = lcnt, base = lbase;
  for (u32 t = threadIdx.x; t < n; t += 256) {
    u32 p = base + t;
    if (p < CAP) cd[p] = lbuf[t];
    else atomicOr(&flags[img], 1u);
  }
}

// ------- fallback: one block per image, exact recapture (early-exits on hot path) -------
__global__ __launch_bounds__(1024) void k_fb(const float* __restrict__ conf,
                                             const u32* __restrict__ cnt001,
                                             const u32* __restrict__ flags,
                                             u32* __restrict__ ncand,
                                             u64* __restrict__ cand) {
  const int img = blockIdx.x;
  const int tid = threadIdx.x;
  {
    u32 nc = ncand[img * S16];
    u32 c1 = cnt001[img * S16];
    bool fb = (flags[img] != 0u) || (nc < TOPK && nc < c1);
    if (!fb) return;                        // uniform across block
  }
  __shared__ u32 ph[8192];                  // 16384 u16-packed bins, 32 KB
  __shared__ u32 csum[1024];                // 4 KB
  __shared__ u32 s_T, s_lcnt;
  for (int b = tid; b < 8192; b += 1024) ph[b] = 0u;
  if (tid == 0) { s_T = 0u; s_lcnt = 0u; }
  __syncthreads();
  const float4* cp = ((const float4*)conf) + (size_t)img * (NPRI/2);
  // pass A: histogram positives on bits>>17
  for (int i = tid; i < NPRI/2; i += 1024) {
    float4 v = cp[i];
    if (v.y > 0.01f) { u32 b = __float_as_uint(v.y) >> 17; atomicAdd(&ph[b >> 1], 1u << ((b & 1) * 16)); }
    if (v.w > 0.01f) { u32 b = __float_as_uint(v.w) >> 17; atomicAdd(&ph[b >> 1], 1u << ((b & 1) * 16)); }
  }
  __syncthreads();
  // chunk sums (16 bins = 8 words per thread) + suffix scan
  {
    u32 acc = 0;
    #pragma unroll
    for (int w = 0; w < 8; ++w) { u32 v = ph[tid*8 + w]; acc += (v & 0xFFFFu) + (v >> 16); }
    csum[tid] = acc;
  }
  __syncthreads();
  for (int off = 1; off < 1024; off <<= 1) {
    u32 v = (tid + off < 1024) ? csum[tid + off] : 0u;
    __syncthreads();
    csum[tid] += v;
    __syncthreads();
  }
  {
    u32 mine = csum[tid], nxt = (tid < 1023) ? csum[tid + 1] : 0u;
    if (mine >= TOPK && nxt < TOPK) {       // unique thread; if total<TOPK, s_T stays 0
      u32 run = nxt;
      for (int b = 15; b >= 0; --b) {
        u32 bin = tid*16 + b;
        u32 w = ph[bin >> 1];
        run += (bin & 1) ? (w >> 16) : (w & 0xFFFFu);
        if (run >= TOPK) { s_T = bin; break; }
      }
    }
  }
  __syncthreads();
  const u32 T = s_T;
  u64* cd = cand + (size_t)img * CAP;
  // pass B: capture all positives with bin >= T
  for (int i = tid; i < NPRI/2; i += 1024) {
    float4 v = cp[i];
    if (v.y > 0.01f) {
      u32 bits = __float_as_uint(v.y);
      if ((bits >> 17) >= T) { u32 p = atomicAdd(&s_lcnt, 1u); if (p < CAP) cd[p] = ((u64)bits << 32) | (u64)(0xFFFFFFFFu - (u32)(2*i)); }
    }
    if (v.w > 0.01f) {
      u32 bits = __float_as_uint(v.w);
      if ((bits >> 17) >= T) { u32 p = atomicAdd(&s_lcnt, 1u); if (p < CAP) cd[p] = ((u64)bits << 32) | (u64)(0xFFFFFFFFu - (u32)(2*i+1)); }
    }
  }
  __syncthreads();
  if (tid == 0) {
    u32 n = s_lcnt; if (n > CAP) n = CAP;
    ncand[img * S16] = n;
  }
}

// ---------------- radix-select + small sort + decode + NMS + emit ----------------
__global__ __launch_bounds__(256) void k_nms(const float* __restrict__ loc,
                                             const float* __restrict__ priors,
                                             const u32* __restrict__ ncand,
                                             const u64* __restrict__ cand,
                                             float* __restrict__ out) {
  __shared__ u64    keys[CAP];        // 32 KB
  __shared__ u32    lh[2048];         // 8 KB
  __shared__ u32    csum[256];        // 1 KB
  __shared__ u64    skeys[512];       // 4 KB
  __shared__ float4 sbox[TOPK];       // 3.2 KB
  __shared__ float  sscore[TOPK];     // 0.8 KB
  __shared__ u64    smask[TOPK*4];    // 6.4 KB
  __shared__ u64    sact[4];
  __shared__ u32    s_TB, s_SC, s_scnt;

  const int img = blockIdx.x;
  const int tid = threadIdx.x;
  u32 nc = ncand[img * S16]; if (nc > CAP) nc = CAP;
  if (nc == 0) return;                       // out pre-zeroed
  const u32 K = (nc < TOPK) ? nc : TOPK;
  const u64* cd = cand + (size_t)img * CAP;

  // load keys + zero histogram
  for (u32 t = tid; t < nc; t += 256) keys[t] = cd[t];
  for (int b = tid; b < 2048; b += 256) lh[b] = 0u;
  if (tid == 0) { s_TB = 0u; s_SC = 0u; s_scnt = 0u; }
  __syncthreads();

  // histogram (bins monotone in score above PRE_BITS; below lumps to 0)
  for (u32 t = tid; t < nc; t += 256) {
    u32 bits = (u32)(keys[t] >> 32);
    u32 bin = (bits >= PRE_BITS) ? ((bits - PRE_BITS) >> 7) : 0u;
    atomicAdd(&lh[bin], 1u);
  }
  __syncthreads();
  // chunk sums (8 bins/thread) + inclusive suffix scan
  {
    u32 acc = 0;
    #pragma unroll
    for (int b = 0; b < 8; ++b) acc += lh[tid*8 + b];
    csum[tid] = acc;
  }
  __syncthreads();
  for (int off = 1; off < 256; off <<= 1) {
    u32 v = (tid + off < 256) ? csum[tid + off] : 0u;
    __syncthreads();
    csum[tid] += v;
    __syncthreads();
  }
  {
    u32 mine = csum[tid], nxt = (tid < 255) ? csum[tid + 1] : 0u;
    if (mine >= K && nxt < K) {              // unique boundary thread
      u32 run = nxt;
      for (int b = 7; b >= 0; --b) {
        run += lh[tid*8 + b];
        if (run >= K) { s_TB = (u32)(tid*8 + b); s_SC = run; break; }
      }
    }
  }
  __syncthreads();
  const u32 TB = s_TB, SC = s_SC;
  const bool generic = (SC > 512u) || (SC < K);

  if (!generic) {
    // compact survivors into skeys, pad, sort (P2 <= 512)
    for (u32 t = tid; t < nc; t += 256) {
      u64 key = keys[t];
      u32 bits = (u32)(key >> 32);
      u32 bin = (bits >= PRE_BITS) ? ((bits - PRE_BITS) >> 7) : 0u;
      if (bin >= TB) { u32 p = atomicAdd(&s_scnt, 1u); skeys[p] = key; }
    }
    __syncthreads();
    u32 P2 = (SC <= 256u) ? 256u : 512u;
    for (u32 t = tid; t < P2; t += 256) if (t >= SC) skeys[t] = 0ull;
    __syncthreads();
    for (u32 k = 2; k <= P2; k <<= 1) {
      for (u32 j = k >> 1; j > 0; j >>= 1) {
        for (u32 t = tid; t < P2; t += 256) {
          u32 x = t ^ j;
          if (x > t) {
            u64 a = skeys[t], b = skeys[x];
            bool up = ((t & k) == 0);
            if (up ? (a < b) : (a > b)) { skeys[t] = b; skeys[x] = a; }
          }
        }
        __syncthreads();
      }
    }
  } else {
    // generic exact path (degenerate data only): full 4096 bitonic
    for (u32 t = tid; t < CAP; t += 256) if (t >= nc) keys[t] = 0ull;
    __syncthreads();
    for (u32 k = 2; k <= CAP; k <<= 1) {
      for (u32 j = k >> 1; j > 0; j >>= 1) {
        for (u32 t = tid; t < CAP; t += 256) {
          u32 x = t ^ j;
          if (x > t) {
            u64 a = keys[t], b = keys[x];
            bool up = ((t & k) == 0);
            if (up ? (a < b) : (a > b)) { keys[t] = b; keys[x] = a; }
          }
        }
        __syncthreads();
      }
    }
    for (u32 t = tid; t < 512; t += 256) skeys[t] = keys[t];
    __syncthreads();
  }

  // ---- decode top-200 ----
  bool valid = false;
  float4 bx = make_float4(0.f, 0.f, 0.f, 0.f);
  float sc = 0.f;
  if (tid < TOPK) {
    u64 key = skeys[tid];
    sc = __uint_as_float((u32)(key >> 32));
    valid = (sc > 0.01f);
    if (valid) {
      u32 idx = 0xFFFFFFFFu - (u32)(key & 0xFFFFFFFFull);
      float4 l = ((const float4*)loc)[(size_t)img * NPRI + idx];
      float4 p = ((const float4*)priors)[idx];
      float cx = p.x + (l.x * 0.1f) * p.z;
      float cy = p.y + (l.y * 0.1f) * p.w;
      float w  = p.z * expf(l.z * 0.2f);
      float h  = p.w * expf(l.w * 0.2f);
      bx = make_float4(cx - w * 0.5f, cy - h * 0.5f, cx + w * 0.5f, cy + h * 0.5f);
    }
    sbox[tid] = bx;
    sscore[tid] = sc;
  }
  {
    u64 bal = __ballot(valid);                // wave w covers slots [64w, 64w+64)
    if ((tid & 63) == 0) sact[tid >> 6] = bal;
  }
  __syncthreads();
  // all-pairs suppression masks (suppress when !(iou <= 0.45); NaN suppresses)
  if (tid < TOPK) {
    float4 bi = sbox[tid];
    float ai = (bi.z - bi.x) * (bi.w - bi.y);
    u64 m0 = 0, m1 = 0, m2 = 0, m3 = 0;
    for (int j = 0; j < TOPK; ++j) {
      float4 bj = sbox[j];
      float ltx = fmaxf(bi.x, bj.x), lty = fmaxf(bi.y, bj.y);
      float rbx = fminf(bi.z, bj.z), rby = fminf(bi.w, bj.w);
      float w = fmaxf(rbx - ltx, 0.f), h = fmaxf(rby - lty, 0.f);
      float inter = w * h;
      float aj = (bj.z - bj.x) * (bj.w - bj.y);
      float uni = ai + aj - inter;
      float iou = inter / uni;
      if (!(iou <= 0.45f)) {
        if      (j < 64)  m0 |= 1ull << j;
        else if (j < 128) m1 |= 1ull << (j - 64);
        else if (j < 192) m2 |= 1ull << (j - 128);
        else              m3 |= 1ull << (j - 192);
      }
    }
    smask[tid*4+0] = m0; smask[tid*4+1] = m1;
    smask[tid*4+2] = m2; smask[tid*4+3] = m3;
  }
  __syncthreads();
  // ---- register-resident greedy sweep on wave 0 ----
  if (tid < 64) {
    u64 r0[4], r1[4], r2[4], r3[4];   // rows tid, 64+tid, 128+tid, 192+tid
    #pragma unroll
    for (int k = 0; k < 4; ++k) {
      r0[k] = smask[tid*4 + k];
      r1[k] = smask[(64 + tid)*4 + k];
      r2[k] = smask[(128 + tid)*4 + k];
      r3[k] = (tid < TOPK - 192) ? smask[(192 + tid)*4 + k] : 0ull;
    }
    u64 a0 = sact[0], a1 = sact[1], a2 = sact[2], a3 = sact[3];
    u64 k0 = 0, k1 = 0, k2 = 0, k3 = 0;
    #pragma unroll
    for (int i = 0; i < TOPK; ++i) {
      const int s = i >> 6, l = i & 63;
      u64 aw = (s == 0) ? a0 : (s == 1) ? a1 : (s == 2) ? a2 : a3;
      if ((aw >> l) & 1ull) {                 // wave-uniform branch
        u64 q0, q1, q2, q3;
        if (s == 0)      { q0=__shfl(r0[0],l); q1=__shfl(r0[1],l); q2=__shfl(r0[2],l); q3=__shfl(r0[3],l); }
        else if (s == 1) { q0=__shfl(r1[0],l); q1=__shfl(r1[1],l); q2=__shfl(r1[2],l); q3=__shfl(r1[3],l); }
        else if (s == 2) { q0=__shfl(r2[0],l); q1=__shfl(r2[1],l); q2=__shfl(r2[2],l); q3=__shfl(r2[3],l); }
        else             { q0=__shfl(r3[0],l); q1=__shfl(r3[1],l); q2=__shfl(r3[2],l); q3=__shfl(r3[3],l); }
        a0 &= ~q0; a1 &= ~q1; a2 &= ~q2; a3 &= ~q3;
        if (s == 0) k0 |= 1ull << l; else if (s == 1) k1 |= 1ull << l;
        else if (s == 2) k2 |= 1ull << l; else k3 |= 1ull << l;
      }
    }
    if (tid == 0) { sact[0] = k0; sact[1] = k1; sact[2] = k2; sact[3] = k3; }
  }
  __syncthreads();
  // ---- emit kept rows, ranked by kept-popcount below ----
  if (tid < TOPK) {
    u64 k0 = sact[0], k1 = sact[1], k2 = sact[2], k3 = sact[3];
    int s = tid >> 6, l = tid & 63;
    u64 w = (s == 0) ? k0 : (s == 1) ? k1 : (s == 2) ? k2 : k3;
    if ((w >> l) & 1ull) {
      u32 rank = __popcll(w & ((1ull << l) - 1ull));
      if (s > 0) rank += __popcll(k0);
      if (s > 1) rank += __popcll(k1);
      if (s > 2) rank += __popcll(k2);
      float4 b = sbox[tid];
      size_t base = (((size_t)img * 2 + 1) * TOPK + (size_t)rank) * 5;
      out[base + 0] = sscore[tid];
      out[base + 1] = b.x; out[base + 2] = b.y;
      out[base + 3] = b.z; out[base + 4] = b.w;
    }
  }
}

extern "C" void kernel_launch(void* const* d_in, const int* in_sizes, int n_in,
                              void* d_out, int out_size, void* d_ws, size_t ws_size,
                              hipStream_t stream) {
  const float* loc    = (const float*)d_in[0];
  const float* conf   = (const float*)d_in[1];
  const float* priors = (const float*)d_in[2];
  float* out = (float*)d_out;

  u32* wsw    = (u32*)d_ws;
  u32* ncand  = wsw + W_NCAND;
  u32* cnt001 = wsw + W_CNT001;
  u32* flags  = wsw + W_FLAGS;
  u64* cand   = (u64*)(wsw + ZWORDS);

  k_zero<<<64, 256, 0, stream>>>(wsw, out);
  k_cap <<<dim3(64, BATCH), 256, 0, stream>>>(conf, ncand, cnt001, cand, flags);
  k_fb  <<<BATCH, 1024, 0, stream>>>(conf, cnt001, flags, ncand, cand);
  k_nms <<<BATCH, 256, 0, stream>>>(loc, priors, ncand, cand, out);
}

// Round 6
// 105.787 us; speedup vs baseline: 1.0365x; 1.0365x over previous
//
#include <hip/hip_runtime.h>

typedef unsigned int u32;
typedef unsigned long long u64;

#define BATCH 32
#define NPRI  200000
#define TOPK  200
#define CAP   4096             // max candidates per image (fallback path can fill this)
#define PRE_BITS 0x3F7F8000u   // bits of 0.998046875f; expected ~391 captures/img
#define LBUF  512              // per-block LDS candidate buffer (k_cap)
#define S16   16               // counter padding (64B lines)

// ws layout (u32 words)
#define W_NCAND  0
#define W_CNT001 (BATCH*S16)
#define W_FLAGS  (W_CNT001 + BATCH*S16)
#define ZWORDS   (W_FLAGS + BATCH)          // *4 bytes, 8B-aligned
#define OUTN     (BATCH*2*TOPK*5)

// ---------------- zero ws counters + output ----------------
__global__ void k_zero(u32* __restrict__ wsw, float* __restrict__ out) {
  int stride = gridDim.x * blockDim.x;
  for (int i = blockIdx.x*blockDim.x + threadIdx.x; i < ZWORDS + OUTN; i += stride) {
    if (i < ZWORDS) wsw[i] = 0u;
    else out[i - ZWORDS] = 0.0f;
  }
}

// ------- hot path: single BW pass, capture scores >= 0.998046875, count positives -------
__global__ __launch_bounds__(256) void k_cap(const float* __restrict__ conf,
                                             u32* __restrict__ ncand,
                                             u32* __restrict__ cnt001,
                                             u64* __restrict__ cand,
                                             u32* __restrict__ flags) {
  __shared__ u64 lbuf[LBUF];          // 4 KB
  __shared__ u32 lcnt, lbase, lc001;
  if (threadIdx.x == 0) { lcnt = 0u; lc001 = 0u; }
  __syncthreads();
  const int img = blockIdx.y;
  const float4* cp = ((const float4*)conf) + (size_t)img * (NPRI/2);
  u32 my001 = 0;
  for (int i = blockIdx.x*256 + threadIdx.x; i < NPRI/2; i += gridDim.x*256) {
    float4 v = cp[i];
    if (v.y > 0.01f) {
      ++my001;
      u32 bits = __float_as_uint(v.y);
      if (bits >= PRE_BITS) {
        u32 p = atomicAdd(&lcnt, 1u);
        if (p < LBUF) lbuf[p] = ((u64)bits << 32) | (u64)(0xFFFFFFFFu - (u32)(2*i));
      }
    }
    if (v.w > 0.01f) {
      ++my001;
      u32 bits = __float_as_uint(v.w);
      if (bits >= PRE_BITS) {
        u32 p = atomicAdd(&lcnt, 1u);
        if (p < LBUF) lbuf[p] = ((u64)bits << 32) | (u64)(0xFFFFFFFFu - (u32)(2*i+1));
      }
    }
  }
  atomicAdd(&lc001, my001);
  __syncthreads();
  if (threadIdx.x == 0) {
    atomicAdd(&cnt001[img * S16], lc001);
    u32 n = lcnt;
    if (n > LBUF) { n = LBUF; atomicOr(&flags[img], 1u); }
    lbase = atomicAdd(&ncand[img * S16], n);
    lcnt = n;
  }
  __syncthreads();
  u64* cd = cand + (size_t)img * CAP;
  u32 n = lcnt, base = lbase;
  for (u32 t = threadIdx.x; t < n; t += 256) {
    u32 p = base + t;
    if (p < CAP) cd[p] = lbuf[t];
    else atomicOr(&flags[img], 1u);
  }
}

// ------- fallback: one block per image, exact recapture (early-exits on hot path) -------
__global__ __launch_bounds__(1024) void k_fb(const float* __restrict__ conf,
                                             const u32* __restrict__ cnt001,
                                             const u32* __restrict__ flags,
                                             u32* __restrict__ ncand,
                                             u64* __restrict__ cand) {
  const int img = blockIdx.x;
  const int tid = threadIdx.x;
  {
    u32 nc = ncand[img * S16];
    u32 c1 = cnt001[img * S16];
    bool fb = (flags[img] != 0u) || (nc < TOPK && nc < c1);
    if (!fb) return;                        // uniform across block
  }
  __shared__ u32 ph[8192];                  // 16384 u16-packed bins, 32 KB
  __shared__ u32 csum[1024];                // 4 KB
  __shared__ u32 s_T, s_lcnt;
  for (int b = tid; b < 8192; b += 1024) ph[b] = 0u;
  if (tid == 0) { s_T = 0u; s_lcnt = 0u; }
  __syncthreads();
  const float4* cp = ((const float4*)conf) + (size_t)img * (NPRI/2);
  // pass A: histogram positives on bits>>17
  for (int i = tid; i < NPRI/2; i += 1024) {
    float4 v = cp[i];
    if (v.y > 0.01f) { u32 b = __float_as_uint(v.y) >> 17; atomicAdd(&ph[b >> 1], 1u << ((b & 1) * 16)); }
    if (v.w > 0.01f) { u32 b = __float_as_uint(v.w) >> 17; atomicAdd(&ph[b >> 1], 1u << ((b & 1) * 16)); }
  }
  __syncthreads();
  // chunk sums (16 bins = 8 words per thread) + suffix scan
  {
    u32 acc = 0;
    #pragma unroll
    for (int w = 0; w < 8; ++w) { u32 v = ph[tid*8 + w]; acc += (v & 0xFFFFu) + (v >> 16); }
    csum[tid] = acc;
  }
  __syncthreads();
  for (int off = 1; off < 1024; off <<= 1) {
    u32 v = (tid + off < 1024) ? csum[tid + off] : 0u;
    __syncthreads();
    csum[tid] += v;
    __syncthreads();
  }
  {
    u32 mine = csum[tid], nxt = (tid < 1023) ? csum[tid + 1] : 0u;
    if (mine >= TOPK && nxt < TOPK) {       // unique thread; if total<TOPK, s_T stays 0
      u32 run = nxt;
      for (int b = 15; b >= 0; --b) {
        u32 bin = tid*16 + b;
        u32 w = ph[bin >> 1];
        run += (bin & 1) ? (w >> 16) : (w & 0xFFFFu);
        if (run >= TOPK) { s_T = bin; break; }
      }
    }
  }
  __syncthreads();
  const u32 T = s_T;
  u64* cd = cand + (size_t)img * CAP;
  // pass B: capture all positives with bin >= T
  for (int i = tid; i < NPRI/2; i += 1024) {
    float4 v = cp[i];
    if (v.y > 0.01f) {
      u32 bits = __float_as_uint(v.y);
      if ((bits >> 17) >= T) { u32 p = atomicAdd(&s_lcnt, 1u); if (p < CAP) cd[p] = ((u64)bits << 32) | (u64)(0xFFFFFFFFu - (u32)(2*i)); }
    }
    if (v.w > 0.01f) {
      u32 bits = __float_as_uint(v.w);
      if ((bits >> 17) >= T) { u32 p = atomicAdd(&s_lcnt, 1u); if (p < CAP) cd[p] = ((u64)bits << 32) | (u64)(0xFFFFFFFFu - (u32)(2*i+1)); }
    }
  }
  __syncthreads();
  if (tid == 0) {
    u32 n = s_lcnt; if (n > CAP) n = CAP;
    ncand[img * S16] = n;
  }
}

// ---------------- small sort + decode + NMS + emit ----------------
__global__ __launch_bounds__(512) void k_nms(const float* __restrict__ loc,
                                             const float* __restrict__ priors,
                                             const u32* __restrict__ ncand,
                                             const u64* __restrict__ cand,
                                             float* __restrict__ out) {
  __shared__ u64    keys[CAP];        // 32 KB (generic fallback path only)
  __shared__ u64    skeys[512];       // 4 KB
  __shared__ float4 sbox[TOPK];       // 3.2 KB
  __shared__ float  sscore[TOPK];     // 0.8 KB
  __shared__ u64    smask[TOPK*4];    // 6.4 KB
  __shared__ u64    sact[4];

  const int img = blockIdx.x;
  const int tid = threadIdx.x;
  u32 nc = ncand[img * S16]; if (nc > CAP) nc = CAP;
  if (nc == 0) return;                       // out pre-zeroed
  const u64* cd = cand + (size_t)img * CAP;

  if (nc <= 512u) {
    // hot path: load + pad + bitonic sort (P2 <= 512, 1 slot/thread)
    u32 P2 = (nc <= 256u) ? 256u : 512u;
    for (u32 t = tid; t < P2; t += 512) skeys[t] = (t < nc) ? cd[t] : 0ull;
    __syncthreads();
    for (u32 k = 2; k <= P2; k <<= 1) {
      for (u32 j = k >> 1; j > 0; j >>= 1) {
        u32 t = (u32)tid;
        if (t < P2) {
          u32 x = t ^ j;
          if (x > t) {
            u64 a = skeys[t], b = skeys[x];
            bool up = ((t & k) == 0);
            if (up ? (a < b) : (a > b)) { skeys[t] = b; skeys[x] = a; }
          }
        }
        __syncthreads();
      }
    }
  } else {
    // generic exact path (degenerate/fallback data only): full 4096 bitonic
    for (u32 t = tid; t < CAP; t += 512) keys[t] = (t < nc) ? cd[t] : 0ull;
    __syncthreads();
    for (u32 k = 2; k <= CAP; k <<= 1) {
      for (u32 j = k >> 1; j > 0; j >>= 1) {
        for (u32 t = tid; t < CAP; t += 512) {
          u32 x = t ^ j;
          if (x > t) {
            u64 a = keys[t], b = keys[x];
            bool up = ((t & k) == 0);
            if (up ? (a < b) : (a > b)) { keys[t] = b; keys[x] = a; }
          }
        }
        __syncthreads();
      }
    }
    if (tid < 512) skeys[tid] = keys[tid];
    __syncthreads();
  }

  // ---- decode top-200 ----
  bool valid = false;
  float4 bx = make_float4(0.f, 0.f, 0.f, 0.f);
  float sc = 0.f;
  if (tid < TOPK) {
    u64 key = skeys[tid];
    sc = __uint_as_float((u32)(key >> 32));
    valid = (sc > 0.01f);
    if (valid) {
      u32 idx = 0xFFFFFFFFu - (u32)(key & 0xFFFFFFFFull);
      float4 l = ((const float4*)loc)[(size_t)img * NPRI + idx];
      float4 p = ((const float4*)priors)[idx];
      float cx = p.x + (l.x * 0.1f) * p.z;
      float cy = p.y + (l.y * 0.1f) * p.w;
      float w  = p.z * expf(l.z * 0.2f);
      float h  = p.w * expf(l.w * 0.2f);
      bx = make_float4(cx - w * 0.5f, cy - h * 0.5f, cx + w * 0.5f, cy + h * 0.5f);
    }
    sbox[tid] = bx;
    sscore[tid] = sc;
  }
  {
    u64 bal = __ballot(valid);                // wave w covers slots [64w, 64w+64)
    if ((tid & 63) == 0 && (tid >> 6) < 4) sact[tid >> 6] = bal;
  }
  __syncthreads();
  // all-pairs suppression masks (suppress when !(iou <= 0.45); NaN suppresses)
  if (tid < TOPK) {
    float4 bi = sbox[tid];
    float ai = (bi.z - bi.x) * (bi.w - bi.y);
    u64 m0 = 0, m1 = 0, m2 = 0, m3 = 0;
    for (int j = 0; j < TOPK; ++j) {
      float4 bj = sbox[j];
      float ltx = fmaxf(bi.x, bj.x), lty = fmaxf(bi.y, bj.y);
      float rbx = fminf(bi.z, bj.z), rby = fminf(bi.w, bj.w);
      float w = fmaxf(rbx - ltx, 0.f), h = fmaxf(rby - lty, 0.f);
      float inter = w * h;
      float aj = (bj.z - bj.x) * (bj.w - bj.y);
      float uni = ai + aj - inter;
      float iou = inter / uni;
      if (!(iou <= 0.45f)) {
        if      (j < 64)  m0 |= 1ull << j;
        else if (j < 128) m1 |= 1ull << (j - 64);
        else if (j < 192) m2 |= 1ull << (j - 128);
        else              m3 |= 1ull << (j - 192);
      }
    }
    smask[tid*4+0] = m0; smask[tid*4+1] = m1;
    smask[tid*4+2] = m2; smask[tid*4+3] = m3;
  }
  __syncthreads();
  // ---- register-resident greedy sweep on wave 0 (NOT unrolled: code-size) ----
  if (tid < 64) {
    u64 r0[4], r1[4], r2[4], r3[4];   // rows tid, 64+tid, 128+tid, 192+tid
    #pragma unroll
    for (int k = 0; k < 4; ++k) {
      r0[k] = smask[tid*4 + k];
      r1[k] = smask[(64 + tid)*4 + k];
      r2[k] = smask[(128 + tid)*4 + k];
      r3[k] = (tid < TOPK - 192) ? smask[(192 + tid)*4 + k] : 0ull;
    }
    u64 a0 = sact[0], a1 = sact[1], a2 = sact[2], a3 = sact[3];
    u64 k0 = 0, k1 = 0, k2 = 0, k3 = 0;
    #pragma unroll 1
    for (int i = 0; i < TOPK; ++i) {
      const int s = i >> 6, l = i & 63;
      u64 aw = (s == 0) ? a0 : (s == 1) ? a1 : (s == 2) ? a2 : a3;
      if ((aw >> l) & 1ull) {                 // wave-uniform branch
        u64 q0, q1, q2, q3;
        if (s == 0)      { q0=__shfl(r0[0],l); q1=__shfl(r0[1],l); q2=__shfl(r0[2],l); q3=__shfl(r0[3],l); }
        else if (s == 1) { q0=__shfl(r1[0],l); q1=__shfl(r1[1],l); q2=__shfl(r1[2],l); q3=__shfl(r1[3],l); }
        else if (s == 2) { q0=__shfl(r2[0],l); q1=__shfl(r2[1],l); q2=__shfl(r2[2],l); q3=__shfl(r2[3],l); }
        else             { q0=__shfl(r3[0],l); q1=__shfl(r3[1],l); q2=__shfl(r3[2],l); q3=__shfl(r3[3],l); }
        a0 &= ~q0; a1 &= ~q1; a2 &= ~q2; a3 &= ~q3;
        if (s == 0) k0 |= 1ull << l; else if (s == 1) k1 |= 1ull << l;
        else if (s == 2) k2 |= 1ull << l; else k3 |= 1ull << l;
      }
    }
    if (tid == 0) { sact[0] = k0; sact[1] = k1; sact[2] = k2; sact[3] = k3; }
  }
  __syncthreads();
  // ---- emit kept rows, ranked by kept-popcount below ----
  if (tid < TOPK) {
    u64 k0 = sact[0], k1 = sact[1], k2 = sact[2], k3 = sact[3];
    int s = tid >> 6, l = tid & 63;
    u64 w = (s == 0) ? k0 : (s == 1) ? k1 : (s == 2) ? k2 : k3;
    if ((w >> l) & 1ull) {
      u32 rank = __popcll(w & ((1ull << l) - 1ull));
      if (s > 0) rank += __popcll(k0);
      if (s > 1) rank += __popcll(k1);
      if (s > 2) rank += __popcll(k2);
      float4 b = sbox[tid];
      size_t base = (((size_t)img * 2 + 1) * TOPK + (size_t)rank) * 5;
      out[base + 0] = sscore[tid];
      out[base + 1] = b.x; out[base + 2] = b.y;
      out[base + 3] = b.z; out[base + 4] = b.w;
    }
  }
}

extern "C" void kernel_launch(void* const* d_in, const int* in_sizes, int n_in,
                              void* d_out, int out_size, void* d_ws, size_t ws_size,
                              hipStream_t stream) {
  const float* loc    = (const float*)d_in[0];
  const float* conf   = (const float*)d_in[1];
  const float* priors = (const float*)d_in[2];
  float* out = (float*)d_out;

  u32* wsw    = (u32*)d_ws;
  u32* ncand  = wsw + W_NCAND;
  u32* cnt001 = wsw + W_CNT001;
  u32* flags  = wsw + W_FLAGS;
  u64* cand   = (u64*)(wsw + ZWORDS);

  k_zero<<<64, 256, 0, stream>>>(wsw, out);
  k_cap <<<dim3(64, BATCH), 256, 0, stream>>>(conf, ncand, cnt001, cand, flags);
  k_fb  <<<BATCH, 1024, 0, stream>>>(conf, cnt001, flags, ncand, cand);
  k_nms <<<BATCH, 512, 0, stream>>>(loc, priors, ncand, cand, out);
}

// Round 8
// 103.561 us; speedup vs baseline: 1.0588x; 1.0215x over previous
//
#include <hip/hip_runtime.h>

typedef unsigned int u32;
typedef unsigned long long u64;

#define BATCH 32
#define NPRI  200000
#define TOPK  200
#define CAP   4096             // max candidates per image (fallback path can fill this)
#define PRE_BITS 0x3F7F8000u   // bits of 0.998046875f; expected ~391 captures/img
#define LBUF  512              // per-block LDS candidate buffer (k_cap)
#define S16   16               // counter padding (64B lines)

// ws layout (u32 words)
#define W_NCAND  0
#define W_CNT001 (BATCH*S16)
#define W_FLAGS  (W_CNT001 + BATCH*S16)
#define ZWORDS   (W_FLAGS + BATCH)          // *4 bytes, 8B-aligned
#define OUTN     (BATCH*2*TOPK*5)

// ---------------- zero ws counters only (out zeroed by k_nms per-image) ----------------
__global__ void k_zero(u32* __restrict__ wsw) {
  int i = blockIdx.x*blockDim.x + threadIdx.x;
  if (i < ZWORDS) wsw[i] = 0u;
}

// ------- hot path: single BW pass, capture scores >= 0.998046875, count positives -------
__global__ __launch_bounds__(256) void k_cap(const float* __restrict__ conf,
                                             u32* __restrict__ ncand,
                                             u32* __restrict__ cnt001,
                                             u64* __restrict__ cand,
                                             u32* __restrict__ flags) {
  __shared__ u64 lbuf[LBUF];          // 4 KB
  __shared__ u32 lcnt, lbase, lc001;
  if (threadIdx.x == 0) { lcnt = 0u; lc001 = 0u; }
  __syncthreads();
  const int img = blockIdx.y;
  const float4* cp = ((const float4*)conf) + (size_t)img * (NPRI/2);
  u32 my001 = 0;
  for (int i = blockIdx.x*256 + threadIdx.x; i < NPRI/2; i += gridDim.x*256) {
    float4 v = cp[i];
    if (v.y > 0.01f) {
      ++my001;
      u32 bits = __float_as_uint(v.y);
      if (bits >= PRE_BITS) {
        u32 p = atomicAdd(&lcnt, 1u);
        if (p < LBUF) lbuf[p] = ((u64)bits << 32) | (u64)(0xFFFFFFFFu - (u32)(2*i));
      }
    }
    if (v.w > 0.01f) {
      ++my001;
      u32 bits = __float_as_uint(v.w);
      if (bits >= PRE_BITS) {
        u32 p = atomicAdd(&lcnt, 1u);
        if (p < LBUF) lbuf[p] = ((u64)bits << 32) | (u64)(0xFFFFFFFFu - (u32)(2*i+1));
      }
    }
  }
  atomicAdd(&lc001, my001);
  __syncthreads();
  if (threadIdx.x == 0) {
    atomicAdd(&cnt001[img * S16], lc001);
    u32 n = lcnt;
    if (n > LBUF) { n = LBUF; atomicOr(&flags[img], 1u); }
    lbase = atomicAdd(&ncand[img * S16], n);
    lcnt = n;
  }
  __syncthreads();
  u64* cd = cand + (size_t)img * CAP;
  u32 n = lcnt, base = lbase;
  for (u32 t = threadIdx.x; t < n; t += 256) {
    u32 p = base + t;
    if (p < CAP) cd[p] = lbuf[t];
    else atomicOr(&flags[img], 1u);
  }
}

// ------- fallback: one block per image, exact recapture (early-exits on hot path) -------
__global__ __launch_bounds__(1024) void k_fb(const float* __restrict__ conf,
                                             const u32* __restrict__ cnt001,
                                             const u32* __restrict__ flags,
                                             u32* __restrict__ ncand,
                                             u64* __restrict__ cand) {
  const int img = blockIdx.x;
  const int tid = threadIdx.x;
  {
    u32 nc = ncand[img * S16];
    u32 c1 = cnt001[img * S16];
    bool fb = (flags[img] != 0u) || (nc < TOPK && nc < c1);
    if (!fb) return;                        // uniform across block
  }
  __shared__ u32 ph[8192];                  // 16384 u16-packed bins, 32 KB
  __shared__ u32 csum[1024];                // 4 KB
  __shared__ u32 s_T, s_lcnt;
  for (int b = tid; b < 8192; b += 1024) ph[b] = 0u;
  if (tid == 0) { s_T = 0u; s_lcnt = 0u; }
  __syncthreads();
  const float4* cp = ((const float4*)conf) + (size_t)img * (NPRI/2);
  // pass A: histogram positives on bits>>17
  for (int i = tid; i < NPRI/2; i += 1024) {
    float4 v = cp[i];
    if (v.y > 0.01f) { u32 b = __float_as_uint(v.y) >> 17; atomicAdd(&ph[b >> 1], 1u << ((b & 1) * 16)); }
    if (v.w > 0.01f) { u32 b = __float_as_uint(v.w) >> 17; atomicAdd(&ph[b >> 1], 1u << ((b & 1) * 16)); }
  }
  __syncthreads();
  // chunk sums (16 bins = 8 words per thread) + suffix scan
  {
    u32 acc = 0;
    #pragma unroll
    for (int w = 0; w < 8; ++w) { u32 v = ph[tid*8 + w]; acc += (v & 0xFFFFu) + (v >> 16); }
    csum[tid] = acc;
  }
  __syncthreads();
  for (int off = 1; off < 1024; off <<= 1) {
    u32 v = (tid + off < 1024) ? csum[tid + off] : 0u;
    __syncthreads();
    csum[tid] += v;
    __syncthreads();
  }
  {
    u32 mine = csum[tid], nxt = (tid < 1023) ? csum[tid + 1] : 0u;
    if (mine >= TOPK && nxt < TOPK) {       // unique thread; if total<TOPK, s_T stays 0
      u32 run = nxt;
      for (int b = 15; b >= 0; --b) {
        u32 bin = tid*16 + b;
        u32 w = ph[bin >> 1];
        run += (bin & 1) ? (w >> 16) : (w & 0xFFFFu);
        if (run >= TOPK) { s_T = bin; break; }
      }
    }
  }
  __syncthreads();
  const u32 T = s_T;
  u64* cd = cand + (size_t)img * CAP;
  // pass B: capture all positives with bin >= T
  for (int i = tid; i < NPRI/2; i += 1024) {
    float4 v = cp[i];
    if (v.y > 0.01f) {
      u32 bits = __float_as_uint(v.y);
      if ((bits >> 17) >= T) { u32 p = atomicAdd(&s_lcnt, 1u); if (p < CAP) cd[p] = ((u64)bits << 32) | (u64)(0xFFFFFFFFu - (u32)(2*i)); }
    }
    if (v.w > 0.01f) {
      u32 bits = __float_as_uint(v.w);
      if ((bits >> 17) >= T) { u32 p = atomicAdd(&s_lcnt, 1u); if (p < CAP) cd[p] = ((u64)bits << 32) | (u64)(0xFFFFFFFFu - (u32)(2*i+1)); }
    }
  }
  __syncthreads();
  if (tid == 0) {
    u32 n = s_lcnt; if (n > CAP) n = CAP;
    ncand[img * S16] = n;
  }
}

// ---------------- rank-sort + decode + NMS + emit (6 barrier phases) ----------------
__global__ __launch_bounds__(512) void k_nms(const float* __restrict__ loc,
                                             const float* __restrict__ priors,
                                             const u32* __restrict__ ncand,
                                             const u64* __restrict__ cand,
                                             float* __restrict__ out) {
  __shared__ u64    lkeys[CAP];       // 32 KB (generic path; hot path uses first 512)
  __shared__ u64    skeys[512];       // 4 KB sorted
  __shared__ float4 sbox[TOPK];
  __shared__ float  sscore[TOPK];
  __shared__ u64    smask[TOPK*4];
  __shared__ u64    sact[4];

  const int img = blockIdx.x;
  const int tid = threadIdx.x;
  float* oimg = out + (size_t)img * 2 * TOPK * 5;

  // phase 1: zero this image's output slab + load keys
  for (int i = tid; i < 2*TOPK*5; i += 512) oimg[i] = 0.0f;
  u32 nc = ncand[img * S16]; if (nc > CAP) nc = CAP;
  if (nc == 0) return;                       // slab zeroed; nothing else to do
  const u64* cd = cand + (size_t)img * CAP;
  const bool hot = (nc <= 512u);
  const u32 ncp = hot ? 512u : ((nc + 7u) & ~7u);
  for (u32 t = tid; t < ncp; t += 512) lkeys[t] = (t < nc) ? cd[t] : 0ull;
  __syncthreads();

  // phase 2: rank sort (keys distinct: index embedded). Scatter skeys[rank]=key.
  if (hot) {
    if (tid < (int)nc) {
      u64 key = lkeys[tid];
      u32 rank = 0;
      for (u32 j = 0; j < 512u; j += 8) {     // LDS broadcast reads, unrolled
        rank += (u32)(lkeys[j+0] > key) + (u32)(lkeys[j+1] > key)
              + (u32)(lkeys[j+2] > key) + (u32)(lkeys[j+3] > key)
              + (u32)(lkeys[j+4] > key) + (u32)(lkeys[j+5] > key)
              + (u32)(lkeys[j+6] > key) + (u32)(lkeys[j+7] > key);
      }
      skeys[rank] = key;                      // ranks unique, < nc
    } else {
      skeys[tid] = 0ull;                      // disjoint slots [nc,512)
    }
  } else {
    u64 myk[8]; u32 myr[8];
    #pragma unroll
    for (int r = 0; r < 8; ++r) {
      u32 g = (u32)tid + ((u32)r << 9);
      myk[r] = (g < ncp) ? lkeys[g] : 0ull;
      myr[r] = 0u;
    }
    for (u32 j = 0; j < ncp; ++j) {
      u64 kj = lkeys[j];
      #pragma unroll
      for (int r = 0; r < 8; ++r) myr[r] += (u32)(kj > myk[r]);
    }
    #pragma unroll
    for (int r = 0; r < 8; ++r) {
      u32 g = (u32)tid + ((u32)r << 9);
      if (g < nc && myr[r] < 512u) skeys[myr[r]] = myk[r];
    }
    // nc > 512 -> every slot of skeys receives exactly one key; no zero-fill needed
  }
  __syncthreads();

  // phase 3: decode top-200
  bool valid = false;
  float4 bx = make_float4(0.f, 0.f, 0.f, 0.f);
  float sc = 0.f;
  if (tid < TOPK) {
    u64 key = skeys[tid];
    sc = __uint_as_float((u32)(key >> 32));
    valid = (sc > 0.01f);
    if (valid) {
      u32 idx = 0xFFFFFFFFu - (u32)(key & 0xFFFFFFFFull);
      float4 l = ((const float4*)loc)[(size_t)img * NPRI + idx];
      float4 p = ((const float4*)priors)[idx];
      float cx = p.x + (l.x * 0.1f) * p.z;
      float cy = p.y + (l.y * 0.1f) * p.w;
      float w  = p.z * expf(l.z * 0.2f);
      float h  = p.w * expf(l.w * 0.2f);
      bx = make_float4(cx - w * 0.5f, cy - h * 0.5f, cx + w * 0.5f, cy + h * 0.5f);
    }
    sbox[tid] = bx;
    sscore[tid] = sc;
  }
  {
    u64 bal = __ballot(valid);                // wave w covers slots [64w, 64w+64)
    if ((tid & 63) == 0 && (tid >> 6) < 4) sact[tid >> 6] = bal;
  }
  __syncthreads();

  // phase 4: all-pairs suppression masks (suppress when !(iou <= 0.45); NaN suppresses)
  if (tid < TOPK) {
    float4 bi = sbox[tid];
    float ai = (bi.z - bi.x) * (bi.w - bi.y);
    u64 m0 = 0, m1 = 0, m2 = 0, m3 = 0;
    for (int j = 0; j < TOPK; ++j) {
      float4 bj = sbox[j];
      float ltx = fmaxf(bi.x, bj.x), lty = fmaxf(bi.y, bj.y);
      float rbx = fminf(bi.z, bj.z), rby = fminf(bi.w, bj.w);
      float w = fmaxf(rbx - ltx, 0.f), h = fmaxf(rby - lty, 0.f);
      float inter = w * h;
      float aj = (bj.z - bj.x) * (bj.w - bj.y);
      float uni = ai + aj - inter;
      float iou = inter / uni;
      if (!(iou <= 0.45f)) {
        if      (j < 64)  m0 |= 1ull << j;
        else if (j < 128) m1 |= 1ull << (j - 64);
        else if (j < 192) m2 |= 1ull << (j - 128);
        else              m3 |= 1ull << (j - 192);
      }
    }
    smask[tid*4+0] = m0; smask[tid*4+1] = m1;
    smask[tid*4+2] = m2; smask[tid*4+3] = m3;
  }
  __syncthreads();

  // phase 5: register-resident greedy sweep on wave 0
  if (tid < 64) {
    u64 r0[4], r1[4], r2[4], r3[4];   // rows tid, 64+tid, 128+tid, 192+tid
    #pragma unroll
    for (int k = 0; k < 4; ++k) {
      r0[k] = smask[tid*4 + k];
      r1[k] = smask[(64 + tid)*4 + k];
      r2[k] = smask[(128 + tid)*4 + k];
      r3[k] = (tid < TOPK - 192) ? smask[(192 + tid)*4 + k] : 0ull;
    }
    u64 a0 = sact[0], a1 = sact[1], a2 = sact[2], a3 = sact[3];
    u64 k0 = 0, k1 = 0, k2 = 0, k3 = 0;
    #pragma unroll 1
    for (int i = 0; i < TOPK; ++i) {
      const int s = i >> 6, l = i & 63;
      u64 aw = (s == 0) ? a0 : (s == 1) ? a1 : (s == 2) ? a2 : a3;
      if ((aw >> l) & 1ull) {                 // wave-uniform branch
        u64 q0, q1, q2, q3;
        if (s == 0)      { q0=__shfl(r0[0],l); q1=__shfl(r0[1],l); q2=__shfl(r0[2],l); q3=__shfl(r0[3],l); }
        else if (s == 1) { q0=__shfl(r1[0],l); q1=__shfl(r1[1],l); q2=__shfl(r1[2],l); q3=__shfl(r1[3],l); }
        else if (s == 2) { q0=__shfl(r2[0],l); q1=__shfl(r2[1],l); q2=__shfl(r2[2],l); q3=__shfl(r2[3],l); }
        else             { q0=__shfl(r3[0],l); q1=__shfl(r3[1],l); q2=__shfl(r3[2],l); q3=__shfl(r3[3],l); }
        a0 &= ~q0; a1 &= ~q1; a2 &= ~q2; a3 &= ~q3;
        if (s == 0) k0 |= 1ull << l; else if (s == 1) k1 |= 1ull << l;
        else if (s == 2) k2 |= 1ull << l; else k3 |= 1ull << l;
      }
    }
    if (tid == 0) { sact[0] = k0; sact[1] = k1; sact[2] = k2; sact[3] = k3; }
  }
  __syncthreads();

  // phase 6: emit kept rows, ranked by kept-popcount below (slab pre-zeroed in phase 1)
  if (tid < TOPK) {
    u64 k0 = sact[0], k1 = sact[1], k2 = sact[2], k3 = sact[3];
    int s = tid >> 6, l = tid & 63;
    u64 w = (s == 0) ? k0 : (s == 1) ? k1 : (s == 2) ? k2 : k3;
    if ((w >> l) & 1ull) {
      u32 rank = __popcll(w & ((1ull << l) - 1ull));
      if (s > 0) rank += __popcll(k0);
      if (s > 1) rank += __popcll(k1);
      if (s > 2) rank += __popcll(k2);
      float4 b = sbox[tid];
      float* row = oimg + ((size_t)TOPK + rank) * 5;   // class-1 plane
      row[0] = sscore[tid];
      row[1] = b.x; row[2] = b.y; row[3] = b.z; row[4] = b.w;
    }
  }
}

extern "C" void kernel_launch(void* const* d_in, const int* in_sizes, int n_in,
                              void* d_out, int out_size, void* d_ws, size_t ws_size,
                              hipStream_t stream) {
  const float* loc    = (const float*)d_in[0];
  const float* conf   = (const float*)d_in[1];
  const float* priors = (const float*)d_in[2];
  float* out = (float*)d_out;

  u32* wsw    = (u32*)d_ws;
  u32* ncand  = wsw + W_NCAND;
  u32* cnt001 = wsw + W_CNT001;
  u32* flags  = wsw + W_FLAGS;
  u64* cand   = (u64*)(wsw + ZWORDS);

  k_zero<<<(ZWORDS + 255)/256, 256, 0, stream>>>(wsw);
  k_cap <<<dim3(64, BATCH), 256, 0, stream>>>(conf, ncand, cnt001, cand, flags);
  k_fb  <<<BATCH, 1024, 0, stream>>>(conf, cnt001, flags, ncand, cand);
  k_nms <<<BATCH, 512, 0, stream>>>(loc, priors, ncand, cand, out);
}

// Round 9
// 93.574 us; speedup vs baseline: 1.1718x; 1.1067x over previous
//
#include <hip/hip_runtime.h>

typedef unsigned int u32;
typedef unsigned long long u64;

#define BATCH 32
#define NPRI  200000
#define TOPK  200
#define CAP   4096             // max candidates per image (fallback can fill this)
#define PRE_BITS 0x3F7F8000u   // bits of 0.998046875f; expected ~391 captures/img
#define NBLK  64               // k_cap blocks per image
#define SEGCAP 128             // candidate slots per (img, blk)

// ws layout: cntA[BATCH*NBLK] u32 | cnt1A[BATCH*NBLK] u32 | cand u64[BATCH*NBLK*SEGCAP]
// every slot is written on every call -> no zero-init kernel needed.

__device__ __forceinline__ u32 binOf(u64 key) {
  u32 bits = (u32)(key >> 32);
  if (bits < PRE_BITS) return 0u;
  u32 b = (bits - PRE_BITS) >> 6;
  return b > 511u ? 511u : b;
}

// ------- pass 1: capture scores >= PRE_BITS into per-block segment; count positives -------
__global__ __launch_bounds__(256) void k_cap(const float* __restrict__ conf,
                                             u32* __restrict__ cntA,
                                             u32* __restrict__ cnt1A,
                                             u64* __restrict__ cand) {
  __shared__ u32 lcnt, lc1;
  if (threadIdx.x == 0) { lcnt = 0u; lc1 = 0u; }
  __syncthreads();
  const int img = blockIdx.y;
  const int blk = blockIdx.x;
  const float4* cp = ((const float4*)conf) + (size_t)img * (NPRI/2);
  u64* cd = cand + ((size_t)img * NBLK + blk) * SEGCAP;
  u32 my001 = 0;
  for (int i = blk*256 + threadIdx.x; i < NPRI/2; i += NBLK*256) {
    float4 v = cp[i];
    if (v.y > 0.01f) {
      ++my001;
      u32 bits = __float_as_uint(v.y);
      if (bits >= PRE_BITS) {
        u32 p = atomicAdd(&lcnt, 1u);
        if (p < SEGCAP) cd[p] = ((u64)bits << 32) | (u64)(0xFFFFFFFFu - (u32)(2*i));
      }
    }
    if (v.w > 0.01f) {
      ++my001;
      u32 bits = __float_as_uint(v.w);
      if (bits >= PRE_BITS) {
        u32 p = atomicAdd(&lcnt, 1u);
        if (p < SEGCAP) cd[p] = ((u64)bits << 32) | (u64)(0xFFFFFFFFu - (u32)(2*i+1));
      }
    }
  }
  if (my001) atomicAdd(&lc1, my001);
  __syncthreads();
  if (threadIdx.x == 0) {
    u32 n = lcnt;
    u32 v = (n > SEGCAP) ? (SEGCAP | 0x80000000u) : n;
    cntA[img * NBLK + blk] = v;
    cnt1A[img * NBLK + blk] = lc1;
  }
}

// ------- gather + hist-scatter sort + decode + IoU + ballot-sweep NMS + emit -------
__global__ __launch_bounds__(512) void k_nms(const float* __restrict__ loc,
                                             const float* __restrict__ priors,
                                             const float* __restrict__ conf,
                                             const u32* __restrict__ cntA,
                                             const u32* __restrict__ cnt1A,
                                             const u64* __restrict__ cand,
                                             float* __restrict__ out) {
  __shared__ u64    lkeys[CAP];       // 32 KB; fallback hist (ph) aliases this
  __shared__ u64    skeys[512];       // 4 KB;  fallback csum aliases this
  __shared__ float4 sbox[TOPK];
  __shared__ float  sscore[TOPK];
  __shared__ u64    smask[4*TOPK];    // [slice][row] -> 8B lane stride on sweep load
  __shared__ u32    suffst[512];
  __shared__ u32    hist[512];
  __shared__ u32    cnt2[512];
  __shared__ u32    pre[NBLK];
  __shared__ u32    ln[NBLK];
  __shared__ u64    sact[4];
  __shared__ u32    s_nc, s_c1, s_flag, s_T, s_ctr;

  const int img = blockIdx.x;
  const int tid = threadIdx.x;
  float* oimg = out + (size_t)img * 2 * TOPK * 5;
  const u64* gseg = cand + (size_t)img * NBLK * SEGCAP;

  // ---- phase 1: zero slab + per-thread zero of hist/cnt2/skeys + wave0 segment scan ----
  for (int i = tid; i < 2*TOPK*5; i += 512) oimg[i] = 0.0f;
  hist[tid & 511] = 0u; cnt2[tid & 511] = 0u; skeys[tid & 511] = 0ull;
  if (tid < 64) {
    u32 v = cntA[img * NBLK + tid];
    u32 n = v & 0x7FFFFFFFu;
    bool ofl = (v >> 31) != 0u;
    u32 c1 = cnt1A[img * NBLK + tid];
    u32 incl = n;
    #pragma unroll
    for (int off = 1; off < 64; off <<= 1) { u32 u = __shfl_up(incl, off); if (tid >= off) incl += u; }
    pre[tid] = incl - n;
    ln[tid] = n;
    u32 tot = __shfl(incl, 63);
    u32 c1s = c1;
    #pragma unroll
    for (int off = 1; off < 64; off <<= 1) c1s += __shfl_xor(c1s, off);
    u64 ob = __ballot(ofl);
    if (tid == 0) { s_nc = tot; s_c1 = c1s; s_flag = (ob != 0ull) ? 1u : 0u; s_T = 0u; s_ctr = 0u; }
  }
  __syncthreads();

  u32 nc = s_nc;
  const bool fb = (s_flag != 0u) || (nc > CAP) || (nc < TOPK && nc < s_c1);
  if (!fb && nc == 0u) return;            // slab zeroed; done

  if (!fb) {
    // ---- gather 64 segments into lkeys ----
    const int b = tid >> 3, r = tid & 7;
    const u32 nb = ln[b], pb = pre[b];
    const u64* sg = gseg + (size_t)b * SEGCAP;
    for (u32 i = r; i < nb; i += 8) lkeys[pb + i] = sg[i];
  } else {
    // ---- exact fallback (correctness-only; never taken on this data) ----
    u32* ph   = (u32*)lkeys;            // 8192 words, 16384 packed u16 bins
    u32* csum = (u32*)skeys;            // 512 chunk sums
    for (int t = tid; t < 8192; t += 512) ph[t] = 0u;
    __syncthreads();
    const float4* cp = ((const float4*)conf) + (size_t)img * (NPRI/2);
    for (int i = tid; i < NPRI/2; i += 512) {
      float4 v = cp[i];
      if (v.y > 0.01f) { u32 b = __float_as_uint(v.y) >> 17; atomicAdd(&ph[b >> 1], 1u << ((b & 1) * 16)); }
      if (v.w > 0.01f) { u32 b = __float_as_uint(v.w) >> 17; atomicAdd(&ph[b >> 1], 1u << ((b & 1) * 16)); }
    }
    __syncthreads();
    {
      u32 acc = 0;
      #pragma unroll
      for (int w = 0; w < 16; ++w) { u32 v = ph[tid*16 + w]; acc += (v & 0xFFFFu) + (v >> 16); }
      csum[tid] = acc;
    }
    __syncthreads();
    for (int off = 1; off < 512; off <<= 1) {
      u32 v = (tid + off < 512) ? csum[tid + off] : 0u;
      __syncthreads();
      csum[tid] += v;
      __syncthreads();
    }
    {
      u32 mine = csum[tid], nxt = (tid < 511) ? csum[tid + 1] : 0u;
      if (mine >= TOPK && nxt < TOPK) {
        u32 run = nxt;
        for (int b = 31; b >= 0; --b) {
          u32 bin = tid*32 + b;
          u32 w = ph[bin >> 1];
          run += (bin & 1) ? (w >> 16) : (w & 0xFFFFu);
          if (run >= TOPK) { s_T = bin; break; }
        }
      }
    }
    __syncthreads();
    const u32 T = s_T;                   // ph dead beyond this point
    __syncthreads();
    for (int i = tid; i < NPRI/2; i += 512) {
      float4 v = cp[i];
      if (v.y > 0.01f) {
        u32 bits = __float_as_uint(v.y);
        if ((bits >> 17) >= T) { u32 p = atomicAdd(&s_ctr, 1u); if (p < CAP) lkeys[p] = ((u64)bits << 32) | (u64)(0xFFFFFFFFu - (u32)(2*i)); }
      }
      if (v.w > 0.01f) {
        u32 bits = __float_as_uint(v.w);
        if ((bits >> 17) >= T) { u32 p = atomicAdd(&s_ctr, 1u); if (p < CAP) lkeys[p] = ((u64)bits << 32) | (u64)(0xFFFFFFFFu - (u32)(2*i+1)); }
      }
    }
    __syncthreads();
    nc = s_ctr; if (nc > CAP) nc = CAP;
    skeys[tid & 511] = 0ull;             // csum aliased skeys; restore zero pad
  }
  __syncthreads();

  // ---- phase 2: sort top-512 into skeys (descending) ----
  if (nc <= 512u) {
    if (tid < (int)nc) atomicAdd(&hist[binOf(lkeys[tid])], 1u);
    __syncthreads();
    if (tid < 64) {
      u32 h[8]; u32 s = 0;
      #pragma unroll
      for (int q = 0; q < 8; ++q) { h[q] = hist[tid*8 + q]; s += h[q]; }
      u32 acc = s;
      #pragma unroll
      for (int off = 1; off < 64; off <<= 1) { u32 v = __shfl_down(acc, off); if (tid + off < 64) acc += v; }
      u32 run = acc - s;                 // keys in higher lanes (higher bins)
      u32 st[8];
      #pragma unroll
      for (int q = 7; q >= 0; --q) { st[q] = run; run += h[q]; }
      #pragma unroll
      for (int q = 0; q < 8; ++q) suffst[tid*8 + q] = st[q];
    }
    __syncthreads();
    u64* tmp = lkeys + 1024;             // free region when nc<=512
    if (tid < (int)nc) {
      u64 key = lkeys[tid]; u32 b = binOf(key);
      u32 pos = suffst[b] + atomicAdd(&cnt2[b], 1u);
      tmp[pos] = key;
    }
    __syncthreads();
    if (tid < (int)nc) {
      u64 k = tmp[tid]; u32 b = binOf(k);
      u32 c = hist[b];
      if (c == 1u) skeys[tid] = k;       // slot == suffst[b]
      else {
        u32 base = suffst[b], r = 0;
        for (u32 q = 0; q < c; ++q) r += (u32)(tmp[base + q] > k);
        skeys[base + r] = k;
      }
    }
  } else {
    // generic exact rank-sort (fallback data only)
    u32 ncp = (nc + 7u) & ~7u;
    for (u32 t = tid; t < ncp; t += 512) if (t >= nc) lkeys[t] = 0ull;
    __syncthreads();
    u64 myk[8]; u32 myr[8];
    #pragma unroll
    for (int r = 0; r < 8; ++r) {
      u32 g = (u32)tid + ((u32)r << 9);
      myk[r] = (g < ncp) ? lkeys[g] : 0ull;
      myr[r] = 0u;
    }
    for (u32 j = 0; j < ncp; ++j) {
      u64 kj = lkeys[j];
      #pragma unroll
      for (int r = 0; r < 8; ++r) myr[r] += (u32)(kj > myk[r]);
    }
    #pragma unroll
    for (int r = 0; r < 8; ++r) {
      u32 g = (u32)tid + ((u32)r << 9);
      if (g < nc && myr[r] < 512u) skeys[myr[r]] = myk[r];
    }
  }
  __syncthreads();

  // ---- phase 3: decode top-200 ----
  bool valid = false;
  float4 bx = make_float4(0.f, 0.f, 0.f, 0.f);
  float sc = 0.f;
  if (tid < TOPK) {
    u64 key = skeys[tid];
    sc = __uint_as_float((u32)(key >> 32));
    valid = (sc > 0.01f);
    if (valid) {
      u32 idx = 0xFFFFFFFFu - (u32)(key & 0xFFFFFFFFull);
      float4 l = ((const float4*)loc)[(size_t)img * NPRI + idx];
      float4 p = ((const float4*)priors)[idx];
      float cx = p.x + (l.x * 0.1f) * p.z;
      float cy = p.y + (l.y * 0.1f) * p.w;
      float w  = p.z * expf(l.z * 0.2f);
      float h  = p.w * expf(l.w * 0.2f);
      bx = make_float4(cx - w * 0.5f, cy - h * 0.5f, cx + w * 0.5f, cy + h * 0.5f);
    }
    sbox[tid] = bx;
    sscore[tid] = sc;
  }
  {
    u64 bal = __ballot(valid);
    if ((tid & 63) == 0 && (tid >> 6) < 4) sact[tid >> 6] = bal;
  }
  __syncthreads();

  // ---- phase 4: suppression masks (suppress when !(iou <= 0.45); NaN suppresses) ----
  if (tid < TOPK) {
    float4 bi = sbox[tid];
    float ai = (bi.z - bi.x) * (bi.w - bi.y);
    u64 m0 = 0, m1 = 0, m2 = 0, m3 = 0;
    for (int j = 0; j < TOPK; ++j) {
      float4 bj = sbox[j];
      float ltx = fmaxf(bi.x, bj.x), lty = fmaxf(bi.y, bj.y);
      float rbx = fminf(bi.z, bj.z), rby = fminf(bi.w, bj.w);
      float w = fmaxf(rbx - ltx, 0.f), h = fmaxf(rby - lty, 0.f);
      float inter = w * h;
      float aj = (bj.z - bj.x) * (bj.w - bj.y);
      float uni = ai + aj - inter;
      float iou = inter / uni;
      if (!(iou <= 0.45f)) {
        if      (j < 64)  m0 |= 1ull << j;
        else if (j < 128) m1 |= 1ull << (j - 64);
        else if (j < 192) m2 |= 1ull << (j - 128);
        else              m3 |= 1ull << (j - 192);
      }
    }
    smask[0*TOPK + tid] = m0; smask[1*TOPK + tid] = m1;
    smask[2*TOPK + tid] = m2; smask[3*TOPK + tid] = m3;
  }
  __syncthreads();

  // ---- phase 5: ballot-based greedy sweep on wave 0 (no LDS in the chain) ----
  // Uses IoU symmetry: mask[i][row] == mask[row][i], so lane j's own row words
  // give the "suppressed-by-i" bits directly.
  if (tid < 64) {
    u64 row0[4], row1[4], row2[4], row3[4];
    #pragma unroll
    for (int s = 0; s < 4; ++s) {
      row0[s] = smask[s*TOPK + tid];
      row1[s] = smask[s*TOPK + 64 + tid];
      row2[s] = smask[s*TOPK + 128 + tid];
      row3[s] = (tid < TOPK - 192) ? smask[s*TOPK + 192 + tid] : 0ull;
    }
    bool a0 = (sact[0] >> tid) & 1ull, a1 = (sact[1] >> tid) & 1ull;
    bool a2 = (sact[2] >> tid) & 1ull, a3 = (sact[3] >> tid) & 1ull;
    u64 k0 = 0, k1 = 0, k2 = 0, k3 = 0;
    #pragma unroll 1
    for (int i = 0; i < TOPK; ++i) {
      const int s = i >> 6, l = i & 63;
      bool a = (s == 0) ? a0 : (s == 1) ? a1 : (s == 2) ? a2 : a3;
      u64 aw = __ballot(a);
      if ((aw >> l) & 1ull) {              // wave-uniform
        a0 = a0 && !((row0[s] >> l) & 1ull);
        a1 = a1 && !((row1[s] >> l) & 1ull);
        a2 = a2 && !((row2[s] >> l) & 1ull);
        a3 = a3 && !((row3[s] >> l) & 1ull);
        if (s == 0) k0 |= 1ull << l; else if (s == 1) k1 |= 1ull << l;
        else if (s == 2) k2 |= 1ull << l; else k3 |= 1ull << l;
      }
    }
    if (tid == 0) { sact[0] = k0; sact[1] = k1; sact[2] = k2; sact[3] = k3; }
  }
  __syncthreads();

  // ---- phase 6: emit kept rows ranked by kept-popcount ----
  if (tid < TOPK) {
    u64 k0 = sact[0], k1 = sact[1], k2 = sact[2], k3 = sact[3];
    int s = tid >> 6, l = tid & 63;
    u64 w = (s == 0) ? k0 : (s == 1) ? k1 : (s == 2) ? k2 : k3;
    if ((w >> l) & 1ull) {
      u32 rank = __popcll(w & ((1ull << l) - 1ull));
      if (s > 0) rank += __popcll(k0);
      if (s > 1) rank += __popcll(k1);
      if (s > 2) rank += __popcll(k2);
      float4 b = sbox[tid];
      float* row = oimg + ((size_t)TOPK + rank) * 5;   // class-1 plane
      row[0] = sscore[tid];
      row[1] = b.x; row[2] = b.y; row[3] = b.z; row[4] = b.w;
    }
  }
}

extern "C" void kernel_launch(void* const* d_in, const int* in_sizes, int n_in,
                              void* d_out, int out_size, void* d_ws, size_t ws_size,
                              hipStream_t stream) {
  const float* loc    = (const float*)d_in[0];
  const float* conf   = (const float*)d_in[1];
  const float* priors = (const float*)d_in[2];
  float* out = (float*)d_out;

  u32* cntA  = (u32*)d_ws;
  u32* cnt1A = cntA + BATCH*NBLK;
  u64* cand  = (u64*)((char*)d_ws + (size_t)2*BATCH*NBLK*4);

  k_cap<<<dim3(NBLK, BATCH), 256, 0, stream>>>(conf, cntA, cnt1A, cand);
  k_nms<<<BATCH, 512, 0, stream>>>(loc, priors, conf, cntA, cnt1A, cand, out);
}

// Round 10
// 76.945 us; speedup vs baseline: 1.4250x; 1.2161x over previous
//
#include <hip/hip_runtime.h>

typedef unsigned int u32;
typedef unsigned long long u64;

#define BATCH 32
#define NPRI  200000
#define TOPK  200
#define CAP   4096             // max candidates per image (fallback can fill this)
#define PRE_BITS 0x3F7F8000u   // bits of 0.998046875f; expected ~391 captures/img
#define NBLK  64               // k_cap blocks per image
#define SEGCAP 128             // candidate slots per (img, blk)

__device__ __forceinline__ u32 binOf(u64 key) {
  u32 bits = (u32)(key >> 32);
  if (bits < PRE_BITS) return 0u;
  u32 b = (bits - PRE_BITS) >> 6;
  return b > 511u ? 511u : b;
}

// ------- pass 1: capture scores >= PRE_BITS into per-block segment; count positives -------
__global__ __launch_bounds__(256) void k_cap(const float* __restrict__ conf,
                                             u32* __restrict__ cntA,
                                             u32* __restrict__ cnt1A,
                                             u64* __restrict__ cand) {
  __shared__ u32 lcnt, lc1;
  if (threadIdx.x == 0) { lcnt = 0u; lc1 = 0u; }
  __syncthreads();
  const int img = blockIdx.y;
  const int blk = blockIdx.x;
  const float4* cp = ((const float4*)conf) + (size_t)img * (NPRI/2);
  u64* cd = cand + ((size_t)img * NBLK + blk) * SEGCAP;
  u32 my001 = 0;
  for (int i = blk*256 + threadIdx.x; i < NPRI/2; i += NBLK*256) {
    float4 v = cp[i];
    if (v.y > 0.01f) {
      ++my001;
      u32 bits = __float_as_uint(v.y);
      if (bits >= PRE_BITS) {
        u32 p = atomicAdd(&lcnt, 1u);
        if (p < SEGCAP) cd[p] = ((u64)bits << 32) | (u64)(0xFFFFFFFFu - (u32)(2*i));
      }
    }
    if (v.w > 0.01f) {
      ++my001;
      u32 bits = __float_as_uint(v.w);
      if (bits >= PRE_BITS) {
        u32 p = atomicAdd(&lcnt, 1u);
        if (p < SEGCAP) cd[p] = ((u64)bits << 32) | (u64)(0xFFFFFFFFu - (u32)(2*i+1));
      }
    }
  }
  if (my001) atomicAdd(&lc1, my001);
  __syncthreads();
  if (threadIdx.x == 0) {
    u32 n = lcnt;
    u32 v = (n > SEGCAP) ? (SEGCAP | 0x80000000u) : n;
    cntA[img * NBLK + blk] = v;
    cnt1A[img * NBLK + blk] = lc1;
  }
}

// ------- gather + hist-scatter sort + decode + slice-parallel IoU + ballot sweep -------
__global__ __launch_bounds__(1024) void k_nms(const float* __restrict__ loc,
                                              const float* __restrict__ priors,
                                              const float* __restrict__ conf,
                                              const u32* __restrict__ cntA,
                                              const u32* __restrict__ cnt1A,
                                              const u64* __restrict__ cand,
                                              float* __restrict__ out) {
  __shared__ u64    lkeys[CAP];       // 32 KB; fallback hist (ph) aliases this
  __shared__ u64    skeys[512];       // 4 KB;  fallback csum aliases this
  __shared__ float4 sbox[TOPK];
  __shared__ float  sscore[TOPK];
  __shared__ u64    smask[4*TOPK];    // [slice][row]
  __shared__ u32    suffst[512];
  __shared__ u32    hist[512];
  __shared__ u32    cnt2[512];
  __shared__ u32    pre[NBLK];
  __shared__ u32    ln[NBLK];
  __shared__ u64    sact[4];
  __shared__ u32    s_nc, s_c1, s_flag, s_T, s_ctr;

  const int img = blockIdx.x;
  const int tid = threadIdx.x;
  float* oimg = out + (size_t)img * 2 * TOPK * 5;
  const u64* gseg = cand + (size_t)img * NBLK * SEGCAP;

  // ---- phase 1: zero slab + zero hist/cnt2/skeys + wave0 segment scan ----
  for (int i = tid; i < 2*TOPK*5; i += 1024) oimg[i] = 0.0f;
  if (tid < 512) { hist[tid] = 0u; cnt2[tid] = 0u; skeys[tid] = 0ull; }
  if (tid < 64) {
    u32 v = cntA[img * NBLK + tid];
    u32 n = v & 0x7FFFFFFFu;
    bool ofl = (v >> 31) != 0u;
    u32 c1 = cnt1A[img * NBLK + tid];
    u32 incl = n;
    #pragma unroll
    for (int off = 1; off < 64; off <<= 1) { u32 u = __shfl_up(incl, off); if (tid >= off) incl += u; }
    pre[tid] = incl - n;
    ln[tid] = n;
    u32 tot = __shfl(incl, 63);
    u32 c1s = c1;
    #pragma unroll
    for (int off = 1; off < 64; off <<= 1) c1s += __shfl_xor(c1s, off);
    u64 ob = __ballot(ofl);
    if (tid == 0) { s_nc = tot; s_c1 = c1s; s_flag = (ob != 0ull) ? 1u : 0u; s_T = 0u; s_ctr = 0u; }
  }
  __syncthreads();

  u32 nc = s_nc;
  const bool fb = (s_flag != 0u) || (nc > CAP) || (nc < TOPK && nc < s_c1);
  if (!fb && nc == 0u) return;            // slab zeroed; done

  if (!fb) {
    // ---- gather 64 segments into lkeys (16 threads per segment) ----
    const int b = tid >> 4, r = tid & 15;
    const u32 nb = ln[b], pb = pre[b];
    const u64* sg = gseg + (size_t)b * SEGCAP;
    for (u32 i = r; i < nb; i += 16) lkeys[pb + i] = sg[i];
  } else {
    // ---- exact fallback (correctness-only; never taken on this data) ----
    u32* ph   = (u32*)lkeys;            // 8192 words, 16384 packed u16 bins
    u32* csum = (u32*)skeys;            // 512 chunk sums
    for (int t = tid; t < 8192; t += 1024) ph[t] = 0u;
    __syncthreads();
    const float4* cp = ((const float4*)conf) + (size_t)img * (NPRI/2);
    for (int i = tid; i < NPRI/2; i += 1024) {
      float4 v = cp[i];
      if (v.y > 0.01f) { u32 b = __float_as_uint(v.y) >> 17; atomicAdd(&ph[b >> 1], 1u << ((b & 1) * 16)); }
      if (v.w > 0.01f) { u32 b = __float_as_uint(v.w) >> 17; atomicAdd(&ph[b >> 1], 1u << ((b & 1) * 16)); }
    }
    __syncthreads();
    if (tid < 512) {
      u32 acc = 0;
      #pragma unroll
      for (int w = 0; w < 16; ++w) { u32 v = ph[tid*16 + w]; acc += (v & 0xFFFFu) + (v >> 16); }
      csum[tid] = acc;
    }
    __syncthreads();
    for (int off = 1; off < 512; off <<= 1) {
      u32 v = (tid < 512 && tid + off < 512) ? csum[tid + off] : 0u;
      __syncthreads();
      if (tid < 512) csum[tid] += v;
      __syncthreads();
    }
    if (tid < 512) {
      u32 mine = csum[tid], nxt = (tid < 511) ? csum[tid + 1] : 0u;
      if (mine >= TOPK && nxt < TOPK) {
        u32 run = nxt;
        for (int b = 31; b >= 0; --b) {
          u32 bin = tid*32 + b;
          u32 w = ph[bin >> 1];
          run += (bin & 1) ? (w >> 16) : (w & 0xFFFFu);
          if (run >= TOPK) { s_T = bin; break; }
        }
      }
    }
    __syncthreads();
    const u32 T = s_T;                   // ph dead beyond this point
    __syncthreads();
    for (int i = tid; i < NPRI/2; i += 1024) {
      float4 v = cp[i];
      if (v.y > 0.01f) {
        u32 bits = __float_as_uint(v.y);
        if ((bits >> 17) >= T) { u32 p = atomicAdd(&s_ctr, 1u); if (p < CAP) lkeys[p] = ((u64)bits << 32) | (u64)(0xFFFFFFFFu - (u32)(2*i)); }
      }
      if (v.w > 0.01f) {
        u32 bits = __float_as_uint(v.w);
        if ((bits >> 17) >= T) { u32 p = atomicAdd(&s_ctr, 1u); if (p < CAP) lkeys[p] = ((u64)bits << 32) | (u64)(0xFFFFFFFFu - (u32)(2*i+1)); }
      }
    }
    __syncthreads();
    nc = s_ctr; if (nc > CAP) nc = CAP;
    if (tid < 512) skeys[tid] = 0ull;    // csum aliased skeys; restore zero pad
  }
  __syncthreads();

  // ---- phase 2: sort top-512 into skeys (descending) ----
  if (nc <= 512u) {
    if (tid < (int)nc) atomicAdd(&hist[binOf(lkeys[tid])], 1u);
    __syncthreads();
    if (tid < 64) {
      u32 h[8]; u32 s = 0;
      #pragma unroll
      for (int q = 0; q < 8; ++q) { h[q] = hist[tid*8 + q]; s += h[q]; }
      u32 acc = s;
      #pragma unroll
      for (int off = 1; off < 64; off <<= 1) { u32 v = __shfl_down(acc, off); if (tid + off < 64) acc += v; }
      u32 run = acc - s;                 // keys in higher lanes (higher bins)
      u32 st[8];
      #pragma unroll
      for (int q = 7; q >= 0; --q) { st[q] = run; run += h[q]; }
      #pragma unroll
      for (int q = 0; q < 8; ++q) suffst[tid*8 + q] = st[q];
    }
    __syncthreads();
    u64* tmp = lkeys + 1024;             // free region when nc<=512
    if (tid < (int)nc) {
      u64 key = lkeys[tid]; u32 b = binOf(key);
      u32 pos = suffst[b] + atomicAdd(&cnt2[b], 1u);
      tmp[pos] = key;
    }
    __syncthreads();
    if (tid < (int)nc) {
      u64 k = tmp[tid]; u32 b = binOf(k);
      u32 c = hist[b];
      if (c == 1u) skeys[tid] = k;       // slot == suffst[b]
      else {
        u32 base = suffst[b], r = 0;
        for (u32 q = 0; q < c; ++q) r += (u32)(tmp[base + q] > k);
        skeys[base + r] = k;
      }
    }
  } else {
    // generic exact rank-sort (fallback data only)
    u32 ncp = (nc + 3u) & ~3u;
    for (u32 t = tid; t < ncp; t += 1024) if (t >= nc) lkeys[t] = 0ull;
    __syncthreads();
    u64 myk[4]; u32 myr[4];
    #pragma unroll
    for (int r = 0; r < 4; ++r) {
      u32 g = (u32)tid + ((u32)r << 10);
      myk[r] = (g < ncp) ? lkeys[g] : 0ull;
      myr[r] = 0u;
    }
    for (u32 j = 0; j < ncp; ++j) {
      u64 kj = lkeys[j];
      #pragma unroll
      for (int r = 0; r < 4; ++r) myr[r] += (u32)(kj > myk[r]);
    }
    #pragma unroll
    for (int r = 0; r < 4; ++r) {
      u32 g = (u32)tid + ((u32)r << 10);
      if (g < nc && myr[r] < 512u) skeys[myr[r]] = myk[r];
    }
  }
  __syncthreads();

  // ---- phase 3: decode top-200 ----
  bool valid = false;
  float4 bx = make_float4(0.f, 0.f, 0.f, 0.f);
  float sc = 0.f;
  if (tid < TOPK) {
    u64 key = skeys[tid];
    sc = __uint_as_float((u32)(key >> 32));
    valid = (sc > 0.01f);
    if (valid) {
      u32 idx = 0xFFFFFFFFu - (u32)(key & 0xFFFFFFFFull);
      float4 l = ((const float4*)loc)[(size_t)img * NPRI + idx];
      float4 p = ((const float4*)priors)[idx];
      float cx = p.x + (l.x * 0.1f) * p.z;
      float cy = p.y + (l.y * 0.1f) * p.w;
      float w  = p.z * expf(l.z * 0.2f);
      float h  = p.w * expf(l.w * 0.2f);
      bx = make_float4(cx - w * 0.5f, cy - h * 0.5f, cx + w * 0.5f, cy + h * 0.5f);
    }
    sbox[tid] = bx;
    sscore[tid] = sc;
  }
  {
    u64 bal = __ballot(valid);
    if ((tid & 63) == 0 && (tid >> 6) < 4) sact[tid >> 6] = bal;
  }
  __syncthreads();

  // ---- phase 4: slice-parallel suppression masks ----
  // thread (s = tid>>8, row = tid&255) computes 64-bit word s of row's mask:
  // bit l set iff !(iou(row, 64s+l) <= 0.45)  (NaN suppresses).
  {
    const int s = tid >> 8;              // 0..3
    const int row = tid & 255;           // 0..255
    if (row < TOPK) {
      float4 bi = sbox[row];
      float ai = (bi.z - bi.x) * (bi.w - bi.y);
      u64 m = 0;
      const int j0 = s * 64;
      const int j1 = (j0 + 64 < TOPK) ? j0 + 64 : TOPK;
      for (int j = j0; j < j1; ++j) {
        float4 bj = sbox[j];
        float ltx = fmaxf(bi.x, bj.x), lty = fmaxf(bi.y, bj.y);
        float rbx = fminf(bi.z, bj.z), rby = fminf(bi.w, bj.w);
        float w = fmaxf(rbx - ltx, 0.f), h = fmaxf(rby - lty, 0.f);
        float inter = w * h;
        float aj = (bj.z - bj.x) * (bj.w - bj.y);
        float uni = ai + aj - inter;
        float iou = inter / uni;
        if (!(iou <= 0.45f)) m |= 1ull << (j - j0);
      }
      smask[s*TOPK + row] = m;
    }
  }
  __syncthreads();

  // ---- phase 5: ballot-based greedy sweep on wave 0 (registers only) ----
  // IoU symmetry: mask[i][row] == mask[row][i].
  if (tid < 64) {
    u64 row0[4], row1[4], row2[4], row3[4];
    #pragma unroll
    for (int s = 0; s < 4; ++s) {
      row0[s] = smask[s*TOPK + tid];
      row1[s] = smask[s*TOPK + 64 + tid];
      row2[s] = smask[s*TOPK + 128 + tid];
      row3[s] = (tid < TOPK - 192) ? smask[s*TOPK + 192 + tid] : 0ull;
    }
    bool a0 = (sact[0] >> tid) & 1ull, a1 = (sact[1] >> tid) & 1ull;
    bool a2 = (sact[2] >> tid) & 1ull, a3 = (sact[3] >> tid) & 1ull;
    u64 k0 = 0, k1 = 0, k2 = 0, k3 = 0;
    #pragma unroll 1
    for (int i = 0; i < TOPK; ++i) {
      const int s = i >> 6, l = i & 63;
      bool a = (s == 0) ? a0 : (s == 1) ? a1 : (s == 2) ? a2 : a3;
      u64 aw = __ballot(a);
      if ((aw >> l) & 1ull) {              // wave-uniform
        a0 = a0 && !((row0[s] >> l) & 1ull);
        a1 = a1 && !((row1[s] >> l) & 1ull);
        a2 = a2 && !((row2[s] >> l) & 1ull);
        a3 = a3 && !((row3[s] >> l) & 1ull);
        if (s == 0) k0 |= 1ull << l; else if (s == 1) k1 |= 1ull << l;
        else if (s == 2) k2 |= 1ull << l; else k3 |= 1ull << l;
      }
    }
    if (tid == 0) { sact[0] = k0; sact[1] = k1; sact[2] = k2; sact[3] = k3; }
  }
  __syncthreads();

  // ---- phase 6: emit kept rows ranked by kept-popcount ----
  if (tid < TOPK) {
    u64 k0 = sact[0], k1 = sact[1], k2 = sact[2], k3 = sact[3];
    int s = tid >> 6, l = tid & 63;
    u64 w = (s == 0) ? k0 : (s == 1) ? k1 : (s == 2) ? k2 : k3;
    if ((w >> l) & 1ull) {
      u32 rank = __popcll(w & ((1ull << l) - 1ull));
      if (s > 0) rank += __popcll(k0);
      if (s > 1) rank += __popcll(k1);
      if (s > 2) rank += __popcll(k2);
      float4 b = sbox[tid];
      float* row = oimg + ((size_t)TOPK + rank) * 5;   // class-1 plane
      row[0] = sscore[tid];
      row[1] = b.x; row[2] = b.y; row[3] = b.z; row[4] = b.w;
    }
  }
}

extern "C" void kernel_launch(void* const* d_in, const int* in_sizes, int n_in,
                              void* d_out, int out_size, void* d_ws, size_t ws_size,
                              hipStream_t stream) {
  const float* loc    = (const float*)d_in[0];
  const float* conf   = (const float*)d_in[1];
  const float* priors = (const float*)d_in[2];
  float* out = (float*)d_out;

  u32* cntA  = (u32*)d_ws;
  u32* cnt1A = cntA + BATCH*NBLK;
  u64* cand  = (u64*)((char*)d_ws + (size_t)2*BATCH*NBLK*4);

  k_cap<<<dim3(NBLK, BATCH), 256, 0, stream>>>(conf, cntA, cnt1A, cand);
  k_nms<<<BATCH, 1024, 0, stream>>>(loc, priors, conf, cntA, cnt1A, cand, out);
}

// Round 11
// 41.616 us; speedup vs baseline: 2.6347x; 1.8489x over previous
//
#include <hip/hip_runtime.h>

typedef unsigned int u32;
typedef unsigned long long u64;

#define BATCH 32
#define NPRI  200000
#define TOPK  200
#define CAP   4096             // max candidates per image (fallback can fill this)
#define PRE_BITS 0x3F7F8000u   // bits of 0.998046875f; expected ~391 captures/img
#define NBLK  64               // k_cap blocks per image
#define SEGCAP 128             // candidate slots per (img, blk)
#define NSLICE 4

__device__ __forceinline__ u32 binOf(u64 key) {
  u32 bits = (u32)(key >> 32);
  if (bits < PRE_BITS) return 0u;
  u32 b = (bits - PRE_BITS) >> 6;
  return b > 511u ? 511u : b;
}

// ------- pass 1: capture scores >= PRE_BITS into per-block segment; count positives -------
__global__ __launch_bounds__(256) void k_cap(const float* __restrict__ conf,
                                             u32* __restrict__ cntA,
                                             u32* __restrict__ cnt1A,
                                             u64* __restrict__ cand) {
  __shared__ u32 lcnt, lc1;
  if (threadIdx.x == 0) { lcnt = 0u; lc1 = 0u; }
  __syncthreads();
  const int img = blockIdx.y;
  const int blk = blockIdx.x;
  const float4* cp = ((const float4*)conf) + (size_t)img * (NPRI/2);
  u64* cd = cand + ((size_t)img * NBLK + blk) * SEGCAP;
  u32 my001 = 0;
  for (int i = blk*256 + threadIdx.x; i < NPRI/2; i += NBLK*256) {
    float4 v = cp[i];
    if (v.y > 0.01f) {
      ++my001;
      u32 bits = __float_as_uint(v.y);
      if (bits >= PRE_BITS) {
        u32 p = atomicAdd(&lcnt, 1u);
        if (p < SEGCAP) cd[p] = ((u64)bits << 32) | (u64)(0xFFFFFFFFu - (u32)(2*i));
      }
    }
    if (v.w > 0.01f) {
      ++my001;
      u32 bits = __float_as_uint(v.w);
      if (bits >= PRE_BITS) {
        u32 p = atomicAdd(&lcnt, 1u);
        if (p < SEGCAP) cd[p] = ((u64)bits << 32) | (u64)(0xFFFFFFFFu - (u32)(2*i+1));
      }
    }
  }
  if (my001) atomicAdd(&lc1, my001);
  __syncthreads();
  if (threadIdx.x == 0) {
    u32 n = lcnt;
    u32 v = (n > SEGCAP) ? (SEGCAP | 0x80000000u) : n;
    cntA[img * NBLK + blk] = v;
    cnt1A[img * NBLK + blk] = lc1;
  }
}

// ------- pass 2: per (img, slice): gather + sort + decode + slice IoU -> ws -------
// 4 blocks per image redundantly sort/decode (deterministic); each computes its
// 64-column slice of the suppression matrix. Slice 0 publishes boxes/scores.
__global__ __launch_bounds__(512) void k_prep(const float* __restrict__ loc,
                                              const float* __restrict__ priors,
                                              const float* __restrict__ conf,
                                              const u32* __restrict__ cntA,
                                              const u32* __restrict__ cnt1A,
                                              const u64* __restrict__ cand,
                                              float4* __restrict__ gbox,
                                              float* __restrict__ gscore,
                                              u32* __restrict__ gmask32) {
  __shared__ u64    lkeys[CAP];       // 32 KB; fallback hist (ph) aliases this
  __shared__ u64    skeys[512];       // 4 KB;  fallback csum aliases this
  __shared__ float4 sbox[TOPK];
  __shared__ float  sarea[TOPK];
  __shared__ float  sscore[TOPK];
  __shared__ u32    suffst[512];
  __shared__ u32    hist[512];
  __shared__ u32    cnt2[512];
  __shared__ u32    pre[NBLK];
  __shared__ u32    ln[NBLK];
  __shared__ u32    s_nc, s_c1, s_flag, s_T, s_ctr;

  const int img = blockIdx.y;
  const int slice = blockIdx.x;
  const int tid = threadIdx.x;
  const u64* gseg = cand + (size_t)img * NBLK * SEGCAP;

  // ---- phase 1: zero hist/cnt2/skeys + wave0 segment scan ----
  hist[tid] = 0u; cnt2[tid] = 0u; skeys[tid] = 0ull;
  if (tid < 64) {
    u32 v = cntA[img * NBLK + tid];
    u32 n = v & 0x7FFFFFFFu;
    bool ofl = (v >> 31) != 0u;
    u32 c1 = cnt1A[img * NBLK + tid];
    u32 incl = n;
    #pragma unroll
    for (int off = 1; off < 64; off <<= 1) { u32 u = __shfl_up(incl, off); if (tid >= off) incl += u; }
    pre[tid] = incl - n;
    ln[tid] = n;
    u32 tot = __shfl(incl, 63);
    u32 c1s = c1;
    #pragma unroll
    for (int off = 1; off < 64; off <<= 1) c1s += __shfl_xor(c1s, off);
    u64 ob = __ballot(ofl);
    if (tid == 0) { s_nc = tot; s_c1 = c1s; s_flag = (ob != 0ull) ? 1u : 0u; s_T = 0u; s_ctr = 0u; }
  }
  __syncthreads();

  u32 nc = s_nc;
  const bool fb = (s_flag != 0u) || (nc > CAP) || (nc < TOPK && nc < s_c1);

  if (!fb) {
    // ---- gather 64 segments into lkeys (8 threads per segment) ----
    const int b = tid >> 3, r = tid & 7;
    const u32 nb = ln[b], pb = pre[b];
    const u64* sg = gseg + (size_t)b * SEGCAP;
    for (u32 i = r; i < nb; i += 8) lkeys[pb + i] = sg[i];
  } else {
    // ---- exact fallback (correctness-only; never taken on this data) ----
    u32* ph   = (u32*)lkeys;            // 8192 words, 16384 packed u16 bins
    u32* csum = (u32*)skeys;            // 512 chunk sums
    for (int t = tid; t < 8192; t += 512) ph[t] = 0u;
    __syncthreads();
    const float4* cp = ((const float4*)conf) + (size_t)img * (NPRI/2);
    for (int i = tid; i < NPRI/2; i += 512) {
      float4 v = cp[i];
      if (v.y > 0.01f) { u32 b = __float_as_uint(v.y) >> 17; atomicAdd(&ph[b >> 1], 1u << ((b & 1) * 16)); }
      if (v.w > 0.01f) { u32 b = __float_as_uint(v.w) >> 17; atomicAdd(&ph[b >> 1], 1u << ((b & 1) * 16)); }
    }
    __syncthreads();
    {
      u32 acc = 0;
      #pragma unroll
      for (int w = 0; w < 16; ++w) { u32 v = ph[tid*16 + w]; acc += (v & 0xFFFFu) + (v >> 16); }
      csum[tid] = acc;
    }
    __syncthreads();
    for (int off = 1; off < 512; off <<= 1) {
      u32 v = (tid + off < 512) ? csum[tid + off] : 0u;
      __syncthreads();
      csum[tid] += v;
      __syncthreads();
    }
    {
      u32 mine = csum[tid], nxt = (tid < 511) ? csum[tid + 1] : 0u;
      if (mine >= TOPK && nxt < TOPK) {
        u32 run = nxt;
        for (int b = 31; b >= 0; --b) {
          u32 bin = tid*32 + b;
          u32 w = ph[bin >> 1];
          run += (bin & 1) ? (w >> 16) : (w & 0xFFFFu);
          if (run >= TOPK) { s_T = bin; break; }
        }
      }
    }
    __syncthreads();
    const u32 T = s_T;                   // ph dead beyond this point
    __syncthreads();
    const float4* cp2 = ((const float4*)conf) + (size_t)img * (NPRI/2);
    for (int i = tid; i < NPRI/2; i += 512) {
      float4 v = cp2[i];
      if (v.y > 0.01f) {
        u32 bits = __float_as_uint(v.y);
        if ((bits >> 17) >= T) { u32 p = atomicAdd(&s_ctr, 1u); if (p < CAP) lkeys[p] = ((u64)bits << 32) | (u64)(0xFFFFFFFFu - (u32)(2*i)); }
      }
      if (v.w > 0.01f) {
        u32 bits = __float_as_uint(v.w);
        if ((bits >> 17) >= T) { u32 p = atomicAdd(&s_ctr, 1u); if (p < CAP) lkeys[p] = ((u64)bits << 32) | (u64)(0xFFFFFFFFu - (u32)(2*i+1)); }
      }
    }
    __syncthreads();
    nc = s_ctr; if (nc > CAP) nc = CAP;
    skeys[tid] = 0ull;                   // csum aliased skeys; restore zero pad
  }
  __syncthreads();

  // ---- phase 2: sort top-512 into skeys (descending); deterministic ----
  if (nc <= 512u) {
    if (tid < (int)nc) atomicAdd(&hist[binOf(lkeys[tid])], 1u);
    __syncthreads();
    if (tid < 64) {
      u32 h[8]; u32 s = 0;
      #pragma unroll
      for (int q = 0; q < 8; ++q) { h[q] = hist[tid*8 + q]; s += h[q]; }
      u32 acc = s;
      #pragma unroll
      for (int off = 1; off < 64; off <<= 1) { u32 v = __shfl_down(acc, off); if (tid + off < 64) acc += v; }
      u32 run = acc - s;                 // keys in higher lanes (higher bins)
      u32 st[8];
      #pragma unroll
      for (int q = 7; q >= 0; --q) { st[q] = run; run += h[q]; }
      #pragma unroll
      for (int q = 0; q < 8; ++q) suffst[tid*8 + q] = st[q];
    }
    __syncthreads();
    u64* tmp = lkeys + 1024;             // free region when nc<=512
    if (tid < (int)nc) {
      u64 key = lkeys[tid]; u32 b = binOf(key);
      u32 pos = suffst[b] + atomicAdd(&cnt2[b], 1u);
      tmp[pos] = key;
    }
    __syncthreads();
    if (tid < (int)nc) {
      u64 k = tmp[tid]; u32 b = binOf(k);
      u32 c = hist[b];
      if (c == 1u) skeys[tid] = k;       // slot == suffst[b]
      else {
        u32 base = suffst[b], r = 0;
        for (u32 q = 0; q < c; ++q) r += (u32)(tmp[base + q] > k);
        skeys[base + r] = k;             // within-bin rank: deterministic
      }
    }
  } else {
    // generic exact rank-sort (fallback data only)
    u32 ncp = (nc + 7u) & ~7u;
    for (u32 t = tid; t < ncp; t += 512) if (t >= nc) lkeys[t] = 0ull;
    __syncthreads();
    u64 myk[8]; u32 myr[8];
    #pragma unroll
    for (int r = 0; r < 8; ++r) {
      u32 g = (u32)tid + ((u32)r << 9);
      myk[r] = (g < ncp) ? lkeys[g] : 0ull;
      myr[r] = 0u;
    }
    for (u32 j = 0; j < ncp; ++j) {
      u64 kj = lkeys[j];
      #pragma unroll
      for (int r = 0; r < 8; ++r) myr[r] += (u32)(kj > myk[r]);
    }
    #pragma unroll
    for (int r = 0; r < 8; ++r) {
      u32 g = (u32)tid + ((u32)r << 9);
      if (g < nc && myr[r] < 512u) skeys[myr[r]] = myk[r];
    }
  }
  __syncthreads();

  // ---- phase 3: decode top-200 (+ areas) ----
  if (tid < TOPK) {
    u64 key = skeys[tid];
    float sc = __uint_as_float((u32)(key >> 32));
    float4 bx = make_float4(0.f, 0.f, 0.f, 0.f);
    if (sc > 0.01f) {
      u32 idx = 0xFFFFFFFFu - (u32)(key & 0xFFFFFFFFull);
      float4 l = ((const float4*)loc)[(size_t)img * NPRI + idx];
      float4 p = ((const float4*)priors)[idx];
      float cx = p.x + (l.x * 0.1f) * p.z;
      float cy = p.y + (l.y * 0.1f) * p.w;
      float w  = p.z * expf(l.z * 0.2f);
      float h  = p.w * expf(l.w * 0.2f);
      bx = make_float4(cx - w * 0.5f, cy - h * 0.5f, cx + w * 0.5f, cy + h * 0.5f);
    } else sc = (sc > 0.01f) ? sc : sc;  // keep raw score for emit threshold
    sbox[tid] = bx;
    sarea[tid] = (bx.z - bx.x) * (bx.w - bx.y);
    sscore[tid] = sc;
  }
  __syncthreads();

  // ---- phase 4: this block's slice of the suppression matrix ----
  // thread (h = tid>>8, row = tid&255): u32 half-word h of word `slice` of row.
  {
    const int h = tid >> 8;              // 0,1
    const int row = tid & 255;
    if (row < TOPK) {
      const int j0 = slice * 64 + h * 32;
      int cnt = TOPK - j0; if (cnt > 32) cnt = 32;
      u32 m = 0;
      float4 bi = sbox[row];
      float ai = sarea[row];
      for (int jj = 0; jj < cnt; ++jj) {
        int j = j0 + jj;
        float4 bj = sbox[j];
        float ltx = fmaxf(bi.x, bj.x), lty = fmaxf(bi.y, bj.y);
        float rbx = fminf(bi.z, bj.z), rby = fminf(bi.w, bj.w);
        float w = fmaxf(rbx - ltx, 0.f), hh = fmaxf(rby - lty, 0.f);
        float inter = w * hh;
        float uni = ai + sarea[j] - inter;
        float iou = inter / uni;
        if (!(iou <= 0.45f)) m |= 1u << jj;
      }
      gmask32[((size_t)img * NSLICE * TOPK + (size_t)slice * TOPK + row) * 2 + h] = m;
    }
  }
  // ---- slice 0 publishes boxes/scores ----
  if (slice == 0 && tid < TOPK) {
    gbox[(size_t)img * TOPK + tid] = sbox[tid];
    gscore[(size_t)img * TOPK + tid] = sscore[tid];
  }
}

// ------- pass 3: greedy sweep (kept-bit skipping) + emit + zero slab -------
__global__ __launch_bounds__(256) void k_sweep(const float4* __restrict__ gbox,
                                               const float* __restrict__ gscore,
                                               const u64* __restrict__ gmask,
                                               float* __restrict__ out) {
  __shared__ float4 sbx[TOPK];
  __shared__ float  ssc[TOPK];
  __shared__ u64    sact[4];
  const int img = blockIdx.x;
  const int tid = threadIdx.x;
  float* oimg = out + (size_t)img * 2 * TOPK * 5;

  for (int i = tid; i < 2*TOPK*5; i += 256) oimg[i] = 0.0f;
  if (tid < TOPK) {
    sbx[tid] = gbox[(size_t)img * TOPK + tid];
    ssc[tid] = gscore[(size_t)img * TOPK + tid];
  }
  __syncthreads();

  if (tid < 64) {
    const u64* gm = gmask + (size_t)img * NSLICE * TOPK;
    u64 row0[4], row1[4], row2[4], row3[4];
    #pragma unroll
    for (int s = 0; s < 4; ++s) {
      row0[s] = gm[s*TOPK + tid];
      row1[s] = gm[s*TOPK + 64 + tid];
      row2[s] = gm[s*TOPK + 128 + tid];
      row3[s] = (tid < TOPK - 192) ? gm[s*TOPK + 192 + tid] : 0ull;
    }
    bool a0 = ssc[tid] > 0.01f;
    bool a1 = ssc[64 + tid] > 0.01f;
    bool a2 = ssc[128 + tid] > 0.01f;
    bool a3 = (tid < TOPK - 192) ? (ssc[192 + tid] > 0.01f) : false;
    u64 k0 = 0, k1 = 0, k2 = 0, k3 = 0;

    #define SWEEP_SLICE(S, AREG, KREG)                                   \
    {                                                                    \
      u64 aw = __ballot(AREG);                                           \
      while (aw) {                                                       \
        int l = __ffsll((long long)aw) - 1;                              \
        KREG |= 1ull << l;                                               \
        a0 = a0 && !((row0[S] >> l) & 1ull);                             \
        a1 = a1 && !((row1[S] >> l) & 1ull);                             \
        a2 = a2 && !((row2[S] >> l) & 1ull);                             \
        a3 = a3 && !((row3[S] >> l) & 1ull);                             \
        u64 above = (l < 63) ? (~0ull << (l + 1)) : 0ull;                \
        aw = __ballot(AREG) & above;                                     \
      }                                                                  \
    }
    SWEEP_SLICE(0, a0, k0)
    SWEEP_SLICE(1, a1, k1)
    SWEEP_SLICE(2, a2, k2)
    SWEEP_SLICE(3, a3, k3)
    #undef SWEEP_SLICE

    if (tid == 0) { sact[0] = k0; sact[1] = k1; sact[2] = k2; sact[3] = k3; }
  }
  __syncthreads();

  if (tid < TOPK) {
    u64 k0 = sact[0], k1 = sact[1], k2 = sact[2], k3 = sact[3];
    int s = tid >> 6, l = tid & 63;
    u64 w = (s == 0) ? k0 : (s == 1) ? k1 : (s == 2) ? k2 : k3;
    if ((w >> l) & 1ull) {
      u32 rank = __popcll(w & ((1ull << l) - 1ull));
      if (s > 0) rank += __popcll(k0);
      if (s > 1) rank += __popcll(k1);
      if (s > 2) rank += __popcll(k2);
      float4 b = sbx[tid];
      float* row = oimg + ((size_t)TOPK + rank) * 5;   // class-1 plane
      row[0] = ssc[tid];
      row[1] = b.x; row[2] = b.y; row[3] = b.z; row[4] = b.w;
    }
  }
}

extern "C" void kernel_launch(void* const* d_in, const int* in_sizes, int n_in,
                              void* d_out, int out_size, void* d_ws, size_t ws_size,
                              hipStream_t stream) {
  const float* loc    = (const float*)d_in[0];
  const float* conf   = (const float*)d_in[1];
  const float* priors = (const float*)d_in[2];
  float* out = (float*)d_out;

  char* w = (char*)d_ws;
  u32* cntA  = (u32*)w;                                  w += (size_t)BATCH*NBLK*4;
  u32* cnt1A = (u32*)w;                                  w += (size_t)BATCH*NBLK*4;
  u64* cand  = (u64*)w;                                  w += (size_t)BATCH*NBLK*SEGCAP*8;
  float4* gbox = (float4*)w;                             w += (size_t)BATCH*TOPK*16;
  float* gscore = (float*)w;                             w += (size_t)BATCH*TOPK*4;
  u64* gmask = (u64*)w;                                  // BATCH*4*TOPK u64

  k_cap  <<<dim3(NBLK, BATCH), 256, 0, stream>>>(conf, cntA, cnt1A, cand);
  k_prep <<<dim3(NSLICE, BATCH), 512, 0, stream>>>(loc, priors, conf, cntA, cnt1A, cand,
                                                   gbox, gscore, (u32*)gmask);
  k_sweep<<<BATCH, 256, 0, stream>>>(gbox, gscore, gmask, out);
}